// Round 12
// baseline (333.424 us; speedup 1.0000x reference)
//
#include <hip/hip_runtime.h>
#include <hip/hip_fp16.h>

#define NN 100000      // nodes
#define NE 1600000     // edges
#define INC 128        // in channels
#define HID 96         // hidden
#define NG 512         // graphs

#define GEMM1_BLOCKS 1563        // ceil(NN/64)
#define REORDER_CHUNKS 6250      // ceil(NE/256)
#define NXCD 8
#define ROLE_NODES 12500         // NN / NXCD
#define G2_BLOCKS 1563           // ceil(NN/64) for MFMA gemm2
#define ZERO_BLOCKS 392          // ceil((NN+1)/256)

typedef _Float16 half8 __attribute__((ext_vector_type(8)));
typedef float f32x4 __attribute__((ext_vector_type(4)));

// ---------------- zero off  +  pack W2 f32->fp16 fragment-order ----------------
__global__ void k_zero_pack(int* __restrict__ off, const float* __restrict__ W2,
                            __half* __restrict__ W2frag) {
    if (blockIdx.x < ZERO_BLOCKS) {
        int i = blockIdx.x * 256 + threadIdx.x;
        if (i < NN + 1) off[i] = 0;
        return;
    }
    int p = (blockIdx.x - ZERO_BLOCKS) * 256 + threadIdx.x;   // (kc,ct,l) id
    if (p >= 3 * 6 * 64) return;
    int kc = p / 384;
    int rem = p - kc * 384;
    int ct = rem >> 6;
    int l = rem & 63;
#pragma unroll
    for (int i = 0; i < 8; ++i) {
        int k = kc * 32 + ((l >> 4) << 3) + i;
        int c = ct * 16 + (l & 15);
        W2frag[p * 8 + i] = __float2half(W2[k * HID + c]);
    }
}

// XCD-partitioned histogram: 8 role-blocks per chunk; role handles its dst range
__global__ void k_hist(const int* __restrict__ dst, int* __restrict__ off) {
    int role = blockIdx.x & 7;
    int chunk = blockIdx.x >> 3;
    int e = chunk * 256 + threadIdx.x;
    if (e >= NE) return;
    int d = dst[e];
    int lo = role * ROLE_NODES;
    if (d >= lo && d < lo + ROLE_NODES) atomicAdd(&off[d + 1], 1);
}

// scan phase 1 + dis (from pre-scan degree) + cur zeroing
__global__ __launch_bounds__(256) void k_scan1(int* __restrict__ a, int* __restrict__ bsum,
                                               float* __restrict__ dis, int* __restrict__ cur,
                                               int n) {
    __shared__ int s[256];
    int base = blockIdx.x * 1024 + threadIdx.x * 4;
    int o0 = (base + 0 < n) ? a[base + 0] : 0;
    int o1 = (base + 1 < n) ? a[base + 1] : 0;
    int o2 = (base + 2 < n) ? a[base + 2] : 0;
    int o3 = (base + 3 < n) ? a[base + 3] : 0;
    if (base + 0 >= 1 && base + 0 < n) dis[base - 1] = rsqrtf((float)(o0 + 1));
    if (base + 1 < n) dis[base + 0] = rsqrtf((float)(o1 + 1));
    if (base + 2 < n) dis[base + 1] = rsqrtf((float)(o2 + 1));
    if (base + 3 < n) dis[base + 2] = rsqrtf((float)(o3 + 1));
#pragma unroll
    for (int j = 0; j < 4; ++j) {
        int idx = base + j;
        if (idx < NN) cur[idx] = 0;
    }
    int v0 = o0, v1 = o1 + v0, v2 = o2 + v1, v3 = o3 + v2;
    s[threadIdx.x] = v3;
    __syncthreads();
    for (int ofs = 1; ofs < 256; ofs <<= 1) {
        int t = (threadIdx.x >= ofs) ? s[threadIdx.x - ofs] : 0;
        __syncthreads();
        s[threadIdx.x] += t;
        __syncthreads();
    }
    int pre = (threadIdx.x > 0) ? s[threadIdx.x - 1] : 0;
    v0 += pre; v1 += pre; v2 += pre; v3 += pre;
    if (base + 0 < n) a[base + 0] = v0;
    if (base + 1 < n) a[base + 1] = v1;
    if (base + 2 < n) a[base + 2] = v2;
    if (base + 3 < n) a[base + 3] = v3;
    if (threadIdx.x == 255) bsum[blockIdx.x] = s[255];
}

// scan phase 2+3 fused
__global__ __launch_bounds__(256) void k_scan3(int* __restrict__ a, const int* __restrict__ bsum,
                                               int n) {
    int b = blockIdx.x;
    if (b == 0) return;
    __shared__ int red[256];
    int t = threadIdx.x;
    red[t] = (t < b) ? bsum[t] : 0;
    __syncthreads();
    for (int s2 = 128; s2; s2 >>= 1) {
        if (t < s2) red[t] += red[t + s2];
        __syncthreads();
    }
    int add = red[0];
    int base = b * 1024 + t * 4;
#pragma unroll
    for (int j = 0; j < 4; ++j) {
        int idx = base + j;
        if (idx < n) a[idx] += add;
    }
}

// ---------------- FUSED: gemm1 ∥ XCD-partitioned reorder ----------------
// reorder: 8 role-blocks per chunk; role = blockIdx&7 (round-robin XCD heuristic);
// each role writes only its contiguous ~1.6MB CSR slice -> single-XCD line ownership.
__global__ __launch_bounds__(256) void k_gemm1_reorder(
        const float* __restrict__ X, const float* __restrict__ W, __half* __restrict__ Yh,
        const int* __restrict__ src, const int* __restrict__ dst,
        const int* __restrict__ off, int* __restrict__ cur,
        const float* __restrict__ dis, int2* __restrict__ ssrcw) {
    __shared__ float xsT[32][64];   // X tile, transposed
    __shared__ float ws[32 * 96];   // W tile
    const int tid = threadIdx.x;

    if (blockIdx.x >= GEMM1_BLOCKS) {
        int rb = blockIdx.x - GEMM1_BLOCKS;
        int role = blockIdx.x & 7;          // actual XCD of this block (round-robin)
        int chunk = rb >> 3;
        int e = chunk * 256 + tid;
        if (e < NE) {
            int d = dst[e];
            int lo = role * ROLE_NODES;
            if (d >= lo && d < lo + ROLE_NODES) {
                int s = src[e];
                int p = off[d] + atomicAdd(&cur[d], 1);
                float w = dis[s] * dis[d];
                ssrcw[p] = make_int2(s, __float_as_int(w));
            }
        }
        return;
    }

    const int row0 = blockIdx.x * 64;
    const int rg = tid >> 4;
    const int cg = tid & 15;
    const int r0 = rg * 4, c0 = cg * 6;
    float acc[4][6] = {};
    const int srow = tid & 63;
    const int sq = tid >> 6;

    for (int k0 = 0; k0 < INC; k0 += 32) {
        {
            int grow = row0 + srow;
            float4 v = make_float4(0.f, 0.f, 0.f, 0.f);
            float4 u = make_float4(0.f, 0.f, 0.f, 0.f);
            if (grow < NN) {
                v = *(const float4*)&X[(size_t)grow * INC + k0 + sq * 4];
                u = *(const float4*)&X[(size_t)grow * INC + k0 + (sq + 4) * 4];
            }
            xsT[sq * 4 + 0][srow] = v.x;
            xsT[sq * 4 + 1][srow] = v.y;
            xsT[sq * 4 + 2][srow] = v.z;
            xsT[sq * 4 + 3][srow] = v.w;
            xsT[(sq + 4) * 4 + 0][srow] = u.x;
            xsT[(sq + 4) * 4 + 1][srow] = u.y;
            xsT[(sq + 4) * 4 + 2][srow] = u.z;
            xsT[(sq + 4) * 4 + 3][srow] = u.w;
        }
        {
            const float4* wsrc = (const float4*)(W + k0 * 96);
            float4* wdst = (float4*)ws;
            wdst[tid] = wsrc[tid];
            wdst[tid + 256] = wsrc[tid + 256];
            wdst[tid + 512] = wsrc[tid + 512];
        }
        __syncthreads();
#pragma unroll
        for (int kk = 0; kk < 32; ++kk) {
            float4 xv = *(const float4*)&xsT[kk][r0];
            float wv[6];
            *(float2*)&wv[0] = *(const float2*)&ws[kk * 96 + c0];
            *(float2*)&wv[2] = *(const float2*)&ws[kk * 96 + c0 + 2];
            *(float2*)&wv[4] = *(const float2*)&ws[kk * 96 + c0 + 4];
            float xr[4] = {xv.x, xv.y, xv.z, xv.w};
#pragma unroll
            for (int i = 0; i < 4; ++i)
#pragma unroll
                for (int j = 0; j < 6; ++j) acc[i][j] += xr[i] * wv[j];
        }
        __syncthreads();
    }
#pragma unroll
    for (int i = 0; i < 4; ++i) {
        int grow = row0 + r0 + i;
        if (grow >= NN) break;
        __half2* yp = (__half2*)&Yh[(size_t)grow * HID + c0];
        yp[0] = __floats2half2_rn(acc[i][0], acc[i][1]);
        yp[1] = __floats2half2_rn(acc[i][2], acc[i][3]);
        yp[2] = __floats2half2_rn(acc[i][4], acc[i][5]);
    }
}

// ---------------- GEMM2 (MFMA fp16, standalone; layout HW-validated round 10) ----------------
__global__ __launch_bounds__(256) void k_gemm2(const __half* __restrict__ Xh,
                                               const __half* __restrict__ W2frag,
                                               __half* __restrict__ Yh) {
    __shared__ __half w2s[9216];
    const int tid = threadIdx.x;
    {
        half8* d8 = (half8*)w2s;
        const half8* s8 = (const half8*)W2frag;
        for (int i = tid; i < 1152; i += 256) d8[i] = s8[i];
    }
    __syncthreads();
    const int w = tid >> 6;
    const int l = tid & 63;
    const int row0 = blockIdx.x * 64 + w * 16;
    int arow = row0 + (l & 15);
    if (arow >= NN) arow = NN - 1;
    f32x4 acc[6] = {};
#pragma unroll
    for (int kc = 0; kc < 3; ++kc) {
        half8 a = *(const half8*)&Xh[(size_t)arow * HID + kc * 32 + ((l >> 4) << 3)];
#pragma unroll
        for (int ct = 0; ct < 6; ++ct) {
            half8 b = *(const half8*)&w2s[((kc * 6 + ct) * 64 + l) * 8];
            acc[ct] = __builtin_amdgcn_mfma_f32_16x16x32_f16(a, b, acc[ct], 0, 0, 0);
        }
    }
    const int orow = row0 + ((l >> 4) << 2);
    const int col = l & 15;
#pragma unroll
    for (int ct = 0; ct < 6; ++ct)
#pragma unroll
        for (int i = 0; i < 4; ++i) {
            int r = orow + i;
            if (r < NN) Yh[(size_t)r * HID + ct * 16 + col] = __float2half(acc[ct][i]);
        }
}

// ---------------- fused GCN aggregation + node-logit partial (16 lanes/dst, half2) ------
template <int PHASE>
__global__ __launch_bounds__(256) void k_agg(const __half* __restrict__ Ah,
                                             const int2* __restrict__ ssrcw,
                                             const int* __restrict__ off,
                                             const float* __restrict__ dis,
                                             const float* __restrict__ bias,
                                             const float* __restrict__ Wn,
                                             const float* __restrict__ bn,
                                             __half* __restrict__ outh,
                                             float* __restrict__ nodeOut) {
    int gid = blockIdx.x * blockDim.x + threadIdx.x;
    int d = gid >> 4;
    int t = gid & 15;
    if (d >= NN) return;
    const int beg = off[d], end = off[d + 1];
    const float dd = dis[d];
    const __half2* ad2 = (const __half2*)(Ah + (size_t)d * HID);
    float2 s0 = __half22float2(ad2[t]);
    float2 s1 = __half22float2(ad2[t + 16]);
    float2 s2 = __half22float2(ad2[t + 32]);
    const float dd2 = dd * dd;
    float a0x = s0.x * dd2, a0y = s0.y * dd2;
    float a1x = s1.x * dd2, a1y = s1.y * dd2;
    float a2x = s2.x * dd2, a2y = s2.y * dd2;
    int j = beg;
    for (; j + 7 < end; j += 8) {
        int2 e[8];
#pragma unroll
        for (int q = 0; q < 8; ++q) e[q] = ssrcw[j + q];
        float w[8];
        const __half2* ap[8];
#pragma unroll
        for (int q = 0; q < 8; ++q) {
            w[q] = __int_as_float(e[q].y);
            ap[q] = (const __half2*)(Ah + (size_t)e[q].x * HID);
        }
        __half2 g0[8], g1[8], g2[8];
#pragma unroll
        for (int q = 0; q < 8; ++q) {
            g0[q] = ap[q][t];
            g1[q] = ap[q][t + 16];
            g2[q] = ap[q][t + 32];
        }
#pragma unroll
        for (int q = 0; q < 8; ++q) {
            float2 f0 = __half22float2(g0[q]);
            float2 f1 = __half22float2(g1[q]);
            float2 f2 = __half22float2(g2[q]);
            a0x += f0.x * w[q]; a0y += f0.y * w[q];
            a1x += f1.x * w[q]; a1y += f1.y * w[q];
            a2x += f2.x * w[q]; a2y += f2.y * w[q];
        }
    }
    for (; j < end; ++j) {
        int2 e0 = ssrcw[j];
        float w0 = __int_as_float(e0.y);
        const __half2* a0 = (const __half2*)(Ah + (size_t)e0.x * HID);
        float2 f0 = __half22float2(a0[t]);
        float2 f1 = __half22float2(a0[t + 16]);
        float2 f2 = __half22float2(a0[t + 32]);
        a0x += f0.x * w0; a0y += f0.y * w0;
        a1x += f1.x * w0; a1y += f1.y * w0;
        a2x += f2.x * w0; a2y += f2.y * w0;
    }
    const float2* b2p = (const float2*)bias;
    float2 b0 = b2p[t], b1 = b2p[t + 16], b2 = b2p[t + 32];
    float h0x = fmaxf(a0x + b0.x, 0.f), h0y = fmaxf(a0y + b0.y, 0.f);
    float h1x = fmaxf(a1x + b1.x, 0.f), h1y = fmaxf(a1y + b1.y, 0.f);
    float h2x = fmaxf(a2x + b2.x, 0.f), h2y = fmaxf(a2y + b2.y, 0.f);
    __half2* o2 = (__half2*)(outh + (size_t)d * HID);
    o2[t]      = __floats2half2_rn(h0x, h0y);
    o2[t + 16] = __floats2half2_rn(h1x, h1y);
    o2[t + 32] = __floats2half2_rn(h2x, h2y);

    const int woff = (PHASE == 1) ? 0 : 96;
    const float2* wn2 = (const float2*)(Wn + woff);
    float2 w0v = wn2[t], w1v = wn2[t + 16], w2v = wn2[t + 32];
    float partial = h0x * w0v.x + h0y * w0v.y + h1x * w1v.x + h1y * w1v.y +
                    h2x * w2v.x + h2y * w2v.y;
#pragma unroll
    for (int m = 8; m; m >>= 1) partial += __shfl_down(partial, m, 16);
    if (t == 0) {
        if (PHASE == 1) nodeOut[d] = partial + bn[0];
        else            nodeOut[d] += partial;
    }
}

// ---------------- graph pooling + graph head (fp16 H inputs) ----------------
__global__ __launch_bounds__(768) void k_pool(const __half* __restrict__ h1,
                                              const __half* __restrict__ h2,
                                              const int* __restrict__ batch,
                                              const float* __restrict__ Wg,
                                              const float* __restrict__ bg,
                                              float* __restrict__ out) {
    int g = blockIdx.x;
    int tid = threadIdx.x;       // 0..767
    int way = tid / 192;         // 0..3
    int f = tid - way * 192;     // 0..191

    int lo = 0, hi = NN;
    while (lo < hi) { int mid = (lo + hi) >> 1; if (batch[mid] < g) lo = mid + 1; else hi = mid; }
    int start = lo;
    hi = NN;
    while (lo < hi) { int mid = (lo + hi) >> 1; if (batch[mid] < g + 1) lo = mid + 1; else hi = mid; }
    int end = lo;

    const __half* hsrc = (f < HID) ? h1 : h2;
    int ff = (f < HID) ? f : f - HID;
    float sum = 0.f, mx = 0.f;  // h >= 0 post-relu
    for (int n = start + way; n < end; n += 4) {
        float v = __half2float(hsrc[(size_t)n * HID + ff]);
        sum += v;
        mx = fmaxf(mx, v);
    }
    __shared__ float rsum[4][192];
    __shared__ float rmax[4][192];
    rsum[way][f] = sum;
    rmax[way][f] = mx;
    __syncthreads();
    if (way == 0) {
        sum = rsum[0][f] + rsum[1][f] + rsum[2][f] + rsum[3][f];
        mx = fmaxf(fmaxf(rmax[0][f], rmax[1][f]), fmaxf(rmax[2][f], rmax[3][f]));
        float cnt = (float)(end - start);
        float mean = sum / fmaxf(cnt, 1.0f);
        rsum[0][f] = mean * Wg[f] + mx * Wg[192 + f];
    }
    __syncthreads();
    if (tid < 64) {
        float acc = rsum[0][tid] + rsum[0][tid + 64] + rsum[0][tid + 128];
#pragma unroll
        for (int m = 32; m; m >>= 1) acc += __shfl_down(acc, m, 64);
        if (tid == 0) out[g] = acc + bg[0];
    }
}

extern "C" void kernel_launch(void* const* d_in, const int* in_sizes, int n_in,
                              void* d_out, int out_size, void* d_ws, size_t ws_size,
                              hipStream_t stream) {
    const float* x    = (const float*)d_in[0];
    const int*   ei   = (const int*)d_in[1];
    const int*   srcp = ei;
    const int*   dstp = ei + NE;
    const int*   batch = (const int*)d_in[2];
    const float* W1 = (const float*)d_in[3];
    const float* b1 = (const float*)d_in[4];
    const float* W2 = (const float*)d_in[5];
    const float* b2 = (const float*)d_in[6];
    const float* Wn = (const float*)d_in[7];
    const float* bn = (const float*)d_in[8];
    const float* Wg = (const float*)d_in[9];
    const float* bg = (const float*)d_in[10];
    float* out = (float*)d_out;

    char* p = (char*)d_ws;
    auto alloc = [&](size_t bytes) {
        char* r = p;
        p += (bytes + 255) & ~(size_t)255;
        return (void*)r;
    };
    float*  dis    = (float*)alloc(NN * 4);
    int*    off    = (int*)alloc((NN + 1) * 4);
    int*    cur    = (int*)alloc(NN * 4);
    int*    bsum   = (int*)alloc(128 * 4);
    int2*   ssrcw  = (int2*)alloc((size_t)NE * 8);
    __half* Ah     = (__half*)alloc((size_t)NN * HID * 2);   // hw buffer (both convs)
    __half* H1h    = (__half*)alloc((size_t)NN * HID * 2);
    __half* H2h    = (__half*)alloc((size_t)NN * HID * 2);
    __half* W2frag = (__half*)alloc(9216 * 2);

    const int TPB = 256;
    const int nScan = NN + 1;
    const int nbScan = (nScan + 1023) / 1024;    // 98

    // prelude
    k_zero_pack<<<ZERO_BLOCKS + 5, TPB, 0, stream>>>(off, W2, W2frag);
    k_hist<<<REORDER_CHUNKS * NXCD, TPB, 0, stream>>>(dstp, off);
    k_scan1<<<nbScan, 256, 0, stream>>>(off, bsum, dis, cur, nScan);
    k_scan3<<<nbScan, 256, 0, stream>>>(off, bsum, nScan);

    // FUSED: gemm1 (blocks 0..1562)  ∥  XCD-partitioned reorder (8 roles x 6250 chunks)
    k_gemm1_reorder<<<GEMM1_BLOCKS + REORDER_CHUNKS * NXCD, 256, 0, stream>>>(
        x, W1, Ah, srcp, dstp, off, cur, dis, ssrcw);

    const int aggThreads = NN * 16;
    float* nodeOut = out + NG;

    // conv1 aggregate (16-lane half2): H1h ; nodeOut partial 1
    k_agg<1><<<(aggThreads + TPB - 1) / TPB, TPB, 0, stream>>>(Ah, ssrcw, off, dis, b1, Wn, bn, H1h, nodeOut);

    // conv2 transform (MFMA, standalone)
    k_gemm2<<<G2_BLOCKS, 256, 0, stream>>>(H1h, W2frag, Ah);

    // conv2 aggregate: H2h ; nodeOut partial 2
    k_agg<2><<<(aggThreads + TPB - 1) / TPB, TPB, 0, stream>>>(Ah, ssrcw, off, dis, b2, Wn, bn, H2h, nodeOut);

    // pooling + graph head
    k_pool<<<NG, 768, 0, stream>>>(H1h, H2h, batch, Wg, bg, out);
}

// Round 13
// 320.625 us; speedup vs baseline: 1.0399x; 1.0399x over previous
//
#include <hip/hip_runtime.h>
#include <hip/hip_fp16.h>

#define NN 100000      // nodes
#define NE 1600000     // edges
#define INC 128        // in channels
#define HID 96         // hidden
#define NG 512         // graphs

#define GEMM1_BLOCKS 1563        // ceil(NN/64)
#define G2_BLOCKS 1563           // ceil(NN/64) for MFMA gemm2
#define ZERO_BLOCKS 392          // ceil((NN+1)/256)
#define HIST_BLOCKS 6250         // ceil(NE/256)

#define BK_SHIFT 9
#define BK_SIZE 512
#define NBK 196                  // ceil(NN/512)
#define A_EPB 16384              // edges per A-pass block
#define A_BLOCKS 98              // ceil(NE/16384)

typedef _Float16 half8 __attribute__((ext_vector_type(8)));
typedef float f32x4 __attribute__((ext_vector_type(4)));

// ---------------- zero off  +  pack W2 f32->fp16 fragment-order ----------------
__global__ void k_zero_pack(int* __restrict__ off, const float* __restrict__ W2,
                            __half* __restrict__ W2frag) {
    if (blockIdx.x < ZERO_BLOCKS) {
        int i = blockIdx.x * 256 + threadIdx.x;
        if (i < NN + 1) off[i] = 0;
        return;
    }
    int p = (blockIdx.x - ZERO_BLOCKS) * 256 + threadIdx.x;   // (kc,ct,l) id
    if (p >= 3 * 6 * 64) return;
    int kc = p / 384;
    int rem = p - kc * 384;
    int ct = rem >> 6;
    int l = rem & 63;
#pragma unroll
    for (int i = 0; i < 8; ++i) {
        int k = kc * 32 + ((l >> 4) << 3) + i;
        int c = ct * 16 + (l & 15);
        W2frag[p * 8 + i] = __float2half(W2[k * HID + c]);
    }
}

// ---------------- FUSED: A1 (bucket histogram, long blocks first) ∥ hist ----------------
__global__ __launch_bounds__(256) void k_hist_a1(const int* __restrict__ dst,
                                                 int* __restrict__ off,
                                                 int* __restrict__ histAB) {
    __shared__ int cnt[NBK];
    const int tid = threadIdx.x;
    if (blockIdx.x < A_BLOCKS) {
        // ---- A1: per-block coarse-bucket histogram ----
        int ab = blockIdx.x;
        for (int i = tid; i < NBK; i += 256) cnt[i] = 0;
        __syncthreads();
        int e0 = ab * A_EPB;
#pragma unroll 4
        for (int q = 0; q < A_EPB / 256; ++q) {
            int e = e0 + q * 256 + tid;
            if (e < NE) atomicAdd(&cnt[dst[e] >> BK_SHIFT], 1);
        }
        __syncthreads();
        for (int i = tid; i < NBK; i += 256) histAB[ab * NBK + i] = cnt[i];
        return;
    }
    // ---- per-node degree histogram ----
    int e = (blockIdx.x - A_BLOCKS) * 256 + tid;
    if (e < NE) atomicAdd(&off[dst[e] + 1], 1);
}

// scan phase 1 + dis (from pre-scan degree)
__global__ __launch_bounds__(256) void k_scan1(int* __restrict__ a, int* __restrict__ bsum,
                                               float* __restrict__ dis, int n) {
    __shared__ int s[256];
    int base = blockIdx.x * 1024 + threadIdx.x * 4;
    int o0 = (base + 0 < n) ? a[base + 0] : 0;
    int o1 = (base + 1 < n) ? a[base + 1] : 0;
    int o2 = (base + 2 < n) ? a[base + 2] : 0;
    int o3 = (base + 3 < n) ? a[base + 3] : 0;
    if (base + 0 >= 1 && base + 0 < n) dis[base - 1] = rsqrtf((float)(o0 + 1));
    if (base + 1 < n) dis[base + 0] = rsqrtf((float)(o1 + 1));
    if (base + 2 < n) dis[base + 1] = rsqrtf((float)(o2 + 1));
    if (base + 3 < n) dis[base + 2] = rsqrtf((float)(o3 + 1));
    int v0 = o0, v1 = o1 + v0, v2 = o2 + v1, v3 = o3 + v2;
    s[threadIdx.x] = v3;
    __syncthreads();
    for (int ofs = 1; ofs < 256; ofs <<= 1) {
        int t = (threadIdx.x >= ofs) ? s[threadIdx.x - ofs] : 0;
        __syncthreads();
        s[threadIdx.x] += t;
        __syncthreads();
    }
    int pre = (threadIdx.x > 0) ? s[threadIdx.x - 1] : 0;
    v0 += pre; v1 += pre; v2 += pre; v3 += pre;
    if (base + 0 < n) a[base + 0] = v0;
    if (base + 1 < n) a[base + 1] = v1;
    if (base + 2 < n) a[base + 2] = v2;
    if (base + 3 < n) a[base + 3] = v3;
    if (threadIdx.x == 255) bsum[blockIdx.x] = s[255];
}

// scan phase 2+3 fused  +  A2 (column prefix of histAB) as last block
__global__ __launch_bounds__(256) void k_scan3_a2(int* __restrict__ a, const int* __restrict__ bsum,
                                                  int* __restrict__ histAB, int n, int nbScan) {
    int b = blockIdx.x;
    int t = threadIdx.x;
    if (b >= nbScan) {
        // ---- A2: exclusive prefix along blocks, per bucket column ----
        if (t < NBK) {
            int run = 0;
            for (int blk = 0; blk < A_BLOCKS; ++blk) {
                int idx = blk * NBK + t;
                int v = histAB[idx];
                histAB[idx] = run;
                run += v;
            }
        }
        return;
    }
    if (b == 0) return;
    __shared__ int red[256];
    red[t] = (t < b) ? bsum[t] : 0;
    __syncthreads();
    for (int s2 = 128; s2; s2 >>= 1) {
        if (t < s2) red[t] += red[t + s2];
        __syncthreads();
    }
    int add = red[0];
    int base = b * 1024 + t * 4;
#pragma unroll
    for (int j = 0; j < 4; ++j) {
        int idx = base + j;
        if (idx < n) a[idx] += add;
    }
}

// ---------------- FUSED: A3 (binned edge write, long blocks first) ∥ gemm1 ----------------
__global__ __launch_bounds__(256) void k_gemm1_a3(
        const float* __restrict__ X, const float* __restrict__ W, __half* __restrict__ Yh,
        const int* __restrict__ src, const int* __restrict__ dst,
        const int* __restrict__ off, const int* __restrict__ histAB,
        unsigned* __restrict__ tmp) {
    __shared__ float xsT[32][64];   // gemm X tile, transposed
    __shared__ float ws[32 * 96];   // gemm W tile
    __shared__ int base[NBK];
    __shared__ int lcnt[NBK];
    const int tid = threadIdx.x;

    if (blockIdx.x < A_BLOCKS) {
        // ---- A3: write packed edges into bucket regions (sequential runs) ----
        int ab = blockIdx.x;
        for (int i = tid; i < NBK; i += 256) {
            base[i] = off[i << BK_SHIFT] + histAB[ab * NBK + i];
            lcnt[i] = 0;
        }
        __syncthreads();
        int e0 = ab * A_EPB;
#pragma unroll 4
        for (int q = 0; q < A_EPB / 256; ++q) {
            int e = e0 + q * 256 + tid;
            if (e < NE) {
                int d = dst[e];
                int bk = d >> BK_SHIFT;
                int lp = atomicAdd(&lcnt[bk], 1);
                tmp[base[bk] + lp] = (unsigned)src[e] | ((unsigned)(d & (BK_SIZE - 1)) << 17);
            }
        }
        return;
    }

    // ---- gemm1 body (K = INC = 128) ----
    const int row0 = (blockIdx.x - A_BLOCKS) * 64;
    const int rg = tid >> 4;
    const int cg = tid & 15;
    const int r0 = rg * 4, c0 = cg * 6;
    float acc[4][6] = {};
    const int srow = tid & 63;
    const int sq = tid >> 6;

    for (int k0 = 0; k0 < INC; k0 += 32) {
        {
            int grow = row0 + srow;
            float4 v = make_float4(0.f, 0.f, 0.f, 0.f);
            float4 u = make_float4(0.f, 0.f, 0.f, 0.f);
            if (grow < NN) {
                v = *(const float4*)&X[(size_t)grow * INC + k0 + sq * 4];
                u = *(const float4*)&X[(size_t)grow * INC + k0 + (sq + 4) * 4];
            }
            xsT[sq * 4 + 0][srow] = v.x;
            xsT[sq * 4 + 1][srow] = v.y;
            xsT[sq * 4 + 2][srow] = v.z;
            xsT[sq * 4 + 3][srow] = v.w;
            xsT[(sq + 4) * 4 + 0][srow] = u.x;
            xsT[(sq + 4) * 4 + 1][srow] = u.y;
            xsT[(sq + 4) * 4 + 2][srow] = u.z;
            xsT[(sq + 4) * 4 + 3][srow] = u.w;
        }
        {
            const float4* wsrc = (const float4*)(W + k0 * 96);
            float4* wdst = (float4*)ws;
            wdst[tid] = wsrc[tid];
            wdst[tid + 256] = wsrc[tid + 256];
            wdst[tid + 512] = wsrc[tid + 512];
        }
        __syncthreads();
#pragma unroll
        for (int kk = 0; kk < 32; ++kk) {
            float4 xv = *(const float4*)&xsT[kk][r0];
            float wv[6];
            *(float2*)&wv[0] = *(const float2*)&ws[kk * 96 + c0];
            *(float2*)&wv[2] = *(const float2*)&ws[kk * 96 + c0 + 2];
            *(float2*)&wv[4] = *(const float2*)&ws[kk * 96 + c0 + 4];
            float xr[4] = {xv.x, xv.y, xv.z, xv.w};
#pragma unroll
            for (int i = 0; i < 4; ++i)
#pragma unroll
                for (int j = 0; j < 6; ++j) acc[i][j] += xr[i] * wv[j];
        }
        __syncthreads();
    }
#pragma unroll
    for (int i = 0; i < 4; ++i) {
        int grow = row0 + r0 + i;
        if (grow >= NN) break;
        __half2* yp = (__half2*)&Yh[(size_t)grow * HID + c0];
        yp[0] = __floats2half2_rn(acc[i][0], acc[i][1]);
        yp[1] = __floats2half2_rn(acc[i][2], acc[i][3]);
        yp[2] = __floats2half2_rn(acc[i][4], acc[i][5]);
    }
}

// ---------------- pass B: per-bucket scatter into final CSR {src, w} ----------------
__global__ __launch_bounds__(256) void k_passB(const unsigned* __restrict__ tmp,
                                               const int* __restrict__ off,
                                               const float* __restrict__ dis,
                                               int2* __restrict__ ssrcw) {
    __shared__ int cnt[BK_SIZE];
    const int tid = threadIdx.x;
    const int nb = blockIdx.x << BK_SHIFT;
    int endNode = nb + BK_SIZE;
    if (endNode > NN) endNode = NN;
    const int rbeg = off[nb], rend = off[endNode];
    for (int i = tid; i < BK_SIZE; i += 256) cnt[i] = 0;
    __syncthreads();
    for (int e = rbeg + tid; e < rend; e += 256) {
        unsigned u = tmp[e];
        int s = (int)(u & 0x1FFFFu);
        int dl = (int)(u >> 17);
        int d = nb + dl;
        int pos = off[d] + atomicAdd(&cnt[dl], 1);
        float w = dis[s] * dis[d];
        ssrcw[pos] = make_int2(s, __float_as_int(w));
    }
}

// ---------------- GEMM2 (MFMA fp16, standalone; layout HW-validated round 10) ----------------
__global__ __launch_bounds__(256) void k_gemm2(const __half* __restrict__ Xh,
                                               const __half* __restrict__ W2frag,
                                               __half* __restrict__ Yh) {
    __shared__ __half w2s[9216];
    const int tid = threadIdx.x;
    {
        half8* d8 = (half8*)w2s;
        const half8* s8 = (const half8*)W2frag;
        for (int i = tid; i < 1152; i += 256) d8[i] = s8[i];
    }
    __syncthreads();
    const int w = tid >> 6;
    const int l = tid & 63;
    const int row0 = blockIdx.x * 64 + w * 16;
    int arow = row0 + (l & 15);
    if (arow >= NN) arow = NN - 1;
    f32x4 acc[6] = {};
#pragma unroll
    for (int kc = 0; kc < 3; ++kc) {
        half8 a = *(const half8*)&Xh[(size_t)arow * HID + kc * 32 + ((l >> 4) << 3)];
#pragma unroll
        for (int ct = 0; ct < 6; ++ct) {
            half8 b = *(const half8*)&w2s[((kc * 6 + ct) * 64 + l) * 8];
            acc[ct] = __builtin_amdgcn_mfma_f32_16x16x32_f16(a, b, acc[ct], 0, 0, 0);
        }
    }
    const int orow = row0 + ((l >> 4) << 2);
    const int col = l & 15;
#pragma unroll
    for (int ct = 0; ct < 6; ++ct)
#pragma unroll
        for (int i = 0; i < 4; ++i) {
            int r = orow + i;
            if (r < NN) Yh[(size_t)r * HID + ct * 16 + col] = __float2half(acc[ct][i]);
        }
}

// ---------------- fused GCN aggregation + node-logit partial (16 lanes/dst, half2) ------
template <int PHASE>
__global__ __launch_bounds__(256) void k_agg(const __half* __restrict__ Ah,
                                             const int2* __restrict__ ssrcw,
                                             const int* __restrict__ off,
                                             const float* __restrict__ dis,
                                             const float* __restrict__ bias,
                                             const float* __restrict__ Wn,
                                             const float* __restrict__ bn,
                                             __half* __restrict__ outh,
                                             float* __restrict__ nodeOut) {
    int gid = blockIdx.x * blockDim.x + threadIdx.x;
    int d = gid >> 4;
    int t = gid & 15;
    if (d >= NN) return;
    const int beg = off[d], end = off[d + 1];
    const float dd = dis[d];
    const __half2* ad2 = (const __half2*)(Ah + (size_t)d * HID);
    float2 s0 = __half22float2(ad2[t]);
    float2 s1 = __half22float2(ad2[t + 16]);
    float2 s2 = __half22float2(ad2[t + 32]);
    const float dd2 = dd * dd;
    float a0x = s0.x * dd2, a0y = s0.y * dd2;
    float a1x = s1.x * dd2, a1y = s1.y * dd2;
    float a2x = s2.x * dd2, a2y = s2.y * dd2;
    int j = beg;
    for (; j + 7 < end; j += 8) {
        int2 e[8];
#pragma unroll
        for (int q = 0; q < 8; ++q) e[q] = ssrcw[j + q];
        float w[8];
        const __half2* ap[8];
#pragma unroll
        for (int q = 0; q < 8; ++q) {
            w[q] = __int_as_float(e[q].y);
            ap[q] = (const __half2*)(Ah + (size_t)e[q].x * HID);
        }
        __half2 g0[8], g1[8], g2[8];
#pragma unroll
        for (int q = 0; q < 8; ++q) {
            g0[q] = ap[q][t];
            g1[q] = ap[q][t + 16];
            g2[q] = ap[q][t + 32];
        }
#pragma unroll
        for (int q = 0; q < 8; ++q) {
            float2 f0 = __half22float2(g0[q]);
            float2 f1 = __half22float2(g1[q]);
            float2 f2 = __half22float2(g2[q]);
            a0x += f0.x * w[q]; a0y += f0.y * w[q];
            a1x += f1.x * w[q]; a1y += f1.y * w[q];
            a2x += f2.x * w[q]; a2y += f2.y * w[q];
        }
    }
    for (; j < end; ++j) {
        int2 e0 = ssrcw[j];
        float w0 = __int_as_float(e0.y);
        const __half2* a0 = (const __half2*)(Ah + (size_t)e0.x * HID);
        float2 f0 = __half22float2(a0[t]);
        float2 f1 = __half22float2(a0[t + 16]);
        float2 f2 = __half22float2(a0[t + 32]);
        a0x += f0.x * w0; a0y += f0.y * w0;
        a1x += f1.x * w0; a1y += f1.y * w0;
        a2x += f2.x * w0; a2y += f2.y * w0;
    }
    const float2* b2p = (const float2*)bias;
    float2 b0 = b2p[t], b1 = b2p[t + 16], b2 = b2p[t + 32];
    float h0x = fmaxf(a0x + b0.x, 0.f), h0y = fmaxf(a0y + b0.y, 0.f);
    float h1x = fmaxf(a1x + b1.x, 0.f), h1y = fmaxf(a1y + b1.y, 0.f);
    float h2x = fmaxf(a2x + b2.x, 0.f), h2y = fmaxf(a2y + b2.y, 0.f);
    __half2* o2 = (__half2*)(outh + (size_t)d * HID);
    o2[t]      = __floats2half2_rn(h0x, h0y);
    o2[t + 16] = __floats2half2_rn(h1x, h1y);
    o2[t + 32] = __floats2half2_rn(h2x, h2y);

    const int woff = (PHASE == 1) ? 0 : 96;
    const float2* wn2 = (const float2*)(Wn + woff);
    float2 w0v = wn2[t], w1v = wn2[t + 16], w2v = wn2[t + 32];
    float partial = h0x * w0v.x + h0y * w0v.y + h1x * w1v.x + h1y * w1v.y +
                    h2x * w2v.x + h2y * w2v.y;
#pragma unroll
    for (int m = 8; m; m >>= 1) partial += __shfl_down(partial, m, 16);
    if (t == 0) {
        if (PHASE == 1) nodeOut[d] = partial + bn[0];
        else            nodeOut[d] += partial;
    }
}

// ---------------- graph pooling + graph head (fp16 H inputs) ----------------
__global__ __launch_bounds__(768) void k_pool(const __half* __restrict__ h1,
                                              const __half* __restrict__ h2,
                                              const int* __restrict__ batch,
                                              const float* __restrict__ Wg,
                                              const float* __restrict__ bg,
                                              float* __restrict__ out) {
    int g = blockIdx.x;
    int tid = threadIdx.x;       // 0..767
    int way = tid / 192;         // 0..3
    int f = tid - way * 192;     // 0..191

    int lo = 0, hi = NN;
    while (lo < hi) { int mid = (lo + hi) >> 1; if (batch[mid] < g) lo = mid + 1; else hi = mid; }
    int start = lo;
    hi = NN;
    while (lo < hi) { int mid = (lo + hi) >> 1; if (batch[mid] < g + 1) lo = mid + 1; else hi = mid; }
    int end = lo;

    const __half* hsrc = (f < HID) ? h1 : h2;
    int ff = (f < HID) ? f : f - HID;
    float sum = 0.f, mx = 0.f;  // h >= 0 post-relu
    for (int n = start + way; n < end; n += 4) {
        float v = __half2float(hsrc[(size_t)n * HID + ff]);
        sum += v;
        mx = fmaxf(mx, v);
    }
    __shared__ float rsum[4][192];
    __shared__ float rmax[4][192];
    rsum[way][f] = sum;
    rmax[way][f] = mx;
    __syncthreads();
    if (way == 0) {
        sum = rsum[0][f] + rsum[1][f] + rsum[2][f] + rsum[3][f];
        mx = fmaxf(fmaxf(rmax[0][f], rmax[1][f]), fmaxf(rmax[2][f], rmax[3][f]));
        float cnt = (float)(end - start);
        float mean = sum / fmaxf(cnt, 1.0f);
        rsum[0][f] = mean * Wg[f] + mx * Wg[192 + f];
    }
    __syncthreads();
    if (tid < 64) {
        float acc = rsum[0][tid] + rsum[0][tid + 64] + rsum[0][tid + 128];
#pragma unroll
        for (int m = 32; m; m >>= 1) acc += __shfl_down(acc, m, 64);
        if (tid == 0) out[g] = acc + bg[0];
    }
}

extern "C" void kernel_launch(void* const* d_in, const int* in_sizes, int n_in,
                              void* d_out, int out_size, void* d_ws, size_t ws_size,
                              hipStream_t stream) {
    const float* x    = (const float*)d_in[0];
    const int*   ei   = (const int*)d_in[1];
    const int*   srcp = ei;
    const int*   dstp = ei + NE;
    const int*   batch = (const int*)d_in[2];
    const float* W1 = (const float*)d_in[3];
    const float* b1 = (const float*)d_in[4];
    const float* W2 = (const float*)d_in[5];
    const float* b2 = (const float*)d_in[6];
    const float* Wn = (const float*)d_in[7];
    const float* bn = (const float*)d_in[8];
    const float* Wg = (const float*)d_in[9];
    const float* bg = (const float*)d_in[10];
    float* out = (float*)d_out;

    char* p = (char*)d_ws;
    auto alloc = [&](size_t bytes) {
        char* r = p;
        p += (bytes + 255) & ~(size_t)255;
        return (void*)r;
    };
    float*    dis    = (float*)alloc(NN * 4);
    int*      off    = (int*)alloc((NN + 1) * 4);
    int*      bsum   = (int*)alloc(128 * 4);
    int*      histAB = (int*)alloc((size_t)A_BLOCKS * NBK * 4);
    unsigned* tmp    = (unsigned*)alloc((size_t)NE * 4);
    int2*     ssrcw  = (int2*)alloc((size_t)NE * 8);
    __half*   Ah     = (__half*)alloc((size_t)NN * HID * 2);   // hw buffer (both convs)
    __half*   H1h    = (__half*)alloc((size_t)NN * HID * 2);
    __half*   H2h    = (__half*)alloc((size_t)NN * HID * 2);
    __half*   W2frag = (__half*)alloc(9216 * 2);

    const int TPB = 256;
    const int nScan = NN + 1;
    const int nbScan = (nScan + 1023) / 1024;    // 98

    // prelude: zero+pack ; [A1 ∥ hist] ; scan1 ; [scan3 ∥ A2]
    k_zero_pack<<<ZERO_BLOCKS + 5, TPB, 0, stream>>>(off, W2, W2frag);
    k_hist_a1<<<A_BLOCKS + HIST_BLOCKS, TPB, 0, stream>>>(dstp, off, histAB);
    k_scan1<<<nbScan, 256, 0, stream>>>(off, bsum, dis, nScan);
    k_scan3_a2<<<nbScan + 1, 256, 0, stream>>>(off, bsum, histAB, nScan, nbScan);

    // FUSED: A3 (binned edge write) ∥ gemm1 ; then pass B builds final CSR
    k_gemm1_a3<<<A_BLOCKS + GEMM1_BLOCKS, 256, 0, stream>>>(
        x, W1, Ah, srcp, dstp, off, histAB, tmp);
    k_passB<<<NBK, 256, 0, stream>>>(tmp, off, dis, ssrcw);

    const int aggThreads = NN * 16;
    float* nodeOut = out + NG;

    // conv1 aggregate (16-lane half2): H1h ; nodeOut partial 1
    k_agg<1><<<(aggThreads + TPB - 1) / TPB, TPB, 0, stream>>>(Ah, ssrcw, off, dis, b1, Wn, bn, H1h, nodeOut);

    // conv2 transform (MFMA, standalone)
    k_gemm2<<<G2_BLOCKS, 256, 0, stream>>>(H1h, W2frag, Ah);

    // conv2 aggregate: H2h ; nodeOut partial 2
    k_agg<2><<<(aggThreads + TPB - 1) / TPB, TPB, 0, stream>>>(Ah, ssrcw, off, dis, b2, Wn, bn, H2h, nodeOut);

    // pooling + graph head
    k_pool<<<NG, 768, 0, stream>>>(H1h, H2h, batch, Wg, bg, out);
}

// Round 14
// 261.701 us; speedup vs baseline: 1.2741x; 1.2252x over previous
//
#include <hip/hip_runtime.h>
#include <hip/hip_fp16.h>

#define NN 100000      // nodes
#define NE 1600000     // edges
#define INC 128        // in channels
#define HID 96         // hidden
#define NG 512         // graphs

#define GEMM1_BLOCKS 1563        // ceil(NN/64)
#define G2_BLOCKS 1563           // ceil(NN/64) for MFMA gemm2

#define BK_SHIFT 9
#define BK_SIZE 512
#define NBK 196                  // ceil(NN/512)
#define A_EPB 16384              // edges per A-pass block
#define A_BLOCKS 98              // ceil(NE/16384)

typedef _Float16 half8 __attribute__((ext_vector_type(8)));
typedef float f32x4 __attribute__((ext_vector_type(4)));

// ---------------- FUSED: A1 (per-block bucket histogram) ∥ W2 pack ----------------
__global__ __launch_bounds__(256) void k_pack_a1(const int* __restrict__ dst,
                                                 int* __restrict__ histAB,
                                                 const float* __restrict__ W2,
                                                 __half* __restrict__ W2frag) {
    const int tid = threadIdx.x;
    if (blockIdx.x < A_BLOCKS) {
        __shared__ int cnt[NBK];
        int ab = blockIdx.x;
        for (int i = tid; i < NBK; i += 256) cnt[i] = 0;
        __syncthreads();
        int e0 = ab * A_EPB;
#pragma unroll 4
        for (int q = 0; q < A_EPB / 256; ++q) {
            int e = e0 + q * 256 + tid;
            if (e < NE) atomicAdd(&cnt[dst[e] >> BK_SHIFT], 1);
        }
        __syncthreads();
        for (int i = tid; i < NBK; i += 256) histAB[ab * NBK + i] = cnt[i];
        return;
    }
    // ---- W2 fragment pack ----
    int p = (blockIdx.x - A_BLOCKS) * 256 + tid;   // (kc,ct,l) id
    if (p >= 3 * 6 * 64) return;
    int kc = p / 384;
    int rem = p - kc * 384;
    int ct = rem >> 6;
    int l = rem & 63;
#pragma unroll
    for (int i = 0; i < 8; ++i) {
        int k = kc * 32 + ((l >> 4) << 3) + i;
        int c = ct * 16 + (l & 15);
        W2frag[p * 8 + i] = __float2half(W2[k * HID + c]);
    }
}

// ---------------- scanS: column prefix of histAB + bucket prefix -> boff ----------------
__global__ __launch_bounds__(256) void k_scanS(int* __restrict__ histAB, int* __restrict__ boff) {
    __shared__ int tot[256];
    int t = threadIdx.x;
    int run = 0;
    if (t < NBK) {
        for (int blk = 0; blk < A_BLOCKS; ++blk) {
            int idx = blk * NBK + t;
            int v = histAB[idx];
            histAB[idx] = run;   // exclusive prefix along blocks
            run += v;
        }
    }
    tot[t] = (t < NBK) ? run : 0;
    __syncthreads();
    for (int ofs = 1; ofs < 256; ofs <<= 1) {
        int v = (t >= ofs) ? tot[t - ofs] : 0;
        __syncthreads();
        tot[t] += v;
        __syncthreads();
    }
    if (t == 0) boff[0] = 0;
    if (t < NBK) boff[t + 1] = tot[t];   // boff[NBK] = NE
}

// ---------------- FUSED: A3 (binned edge write) ∥ gemm1 ----------------
__global__ __launch_bounds__(256) void k_gemm1_a3(
        const float* __restrict__ X, const float* __restrict__ W, __half* __restrict__ Yh,
        const int* __restrict__ src, const int* __restrict__ dst,
        const int* __restrict__ boff, const int* __restrict__ histAB,
        unsigned* __restrict__ tmp) {
    __shared__ float xsT[32][64];   // gemm X tile (A3 overlays base/lcnt here)
    __shared__ float ws[32 * 96];   // gemm W tile
    const int tid = threadIdx.x;

    if (blockIdx.x < A_BLOCKS) {
        int* base = (int*)&xsT[0][0];
        int* lcnt = base + NBK;
        int ab = blockIdx.x;
        for (int i = tid; i < NBK; i += 256) {
            base[i] = boff[i] + histAB[ab * NBK + i];
            lcnt[i] = 0;
        }
        __syncthreads();
        int e0 = ab * A_EPB;
#pragma unroll 4
        for (int q = 0; q < A_EPB / 256; ++q) {
            int e = e0 + q * 256 + tid;
            if (e < NE) {
                int d = dst[e];
                int bk = d >> BK_SHIFT;
                int lp = atomicAdd(&lcnt[bk], 1);
                tmp[base[bk] + lp] = (unsigned)src[e] | ((unsigned)(d & (BK_SIZE - 1)) << 17);
            }
        }
        return;
    }

    // ---- gemm1 body (K = INC = 128) ----
    const int row0 = (blockIdx.x - A_BLOCKS) * 64;
    const int rg = tid >> 4;
    const int cg = tid & 15;
    const int r0 = rg * 4, c0 = cg * 6;
    float acc[4][6] = {};
    const int srow = tid & 63;
    const int sq = tid >> 6;

    for (int k0 = 0; k0 < INC; k0 += 32) {
        {
            int grow = row0 + srow;
            float4 v = make_float4(0.f, 0.f, 0.f, 0.f);
            float4 u = make_float4(0.f, 0.f, 0.f, 0.f);
            if (grow < NN) {
                v = *(const float4*)&X[(size_t)grow * INC + k0 + sq * 4];
                u = *(const float4*)&X[(size_t)grow * INC + k0 + (sq + 4) * 4];
            }
            xsT[sq * 4 + 0][srow] = v.x;
            xsT[sq * 4 + 1][srow] = v.y;
            xsT[sq * 4 + 2][srow] = v.z;
            xsT[sq * 4 + 3][srow] = v.w;
            xsT[(sq + 4) * 4 + 0][srow] = u.x;
            xsT[(sq + 4) * 4 + 1][srow] = u.y;
            xsT[(sq + 4) * 4 + 2][srow] = u.z;
            xsT[(sq + 4) * 4 + 3][srow] = u.w;
        }
        {
            const float4* wsrc = (const float4*)(W + k0 * 96);
            float4* wdst = (float4*)ws;
            wdst[tid] = wsrc[tid];
            wdst[tid + 256] = wsrc[tid + 256];
            wdst[tid + 512] = wsrc[tid + 512];
        }
        __syncthreads();
#pragma unroll
        for (int kk = 0; kk < 32; ++kk) {
            float4 xv = *(const float4*)&xsT[kk][r0];
            float wv[6];
            *(float2*)&wv[0] = *(const float2*)&ws[kk * 96 + c0];
            *(float2*)&wv[2] = *(const float2*)&ws[kk * 96 + c0 + 2];
            *(float2*)&wv[4] = *(const float2*)&ws[kk * 96 + c0 + 4];
            float xr[4] = {xv.x, xv.y, xv.z, xv.w};
#pragma unroll
            for (int i = 0; i < 4; ++i)
#pragma unroll
                for (int j = 0; j < 6; ++j) acc[i][j] += xr[i] * wv[j];
        }
        __syncthreads();
    }
#pragma unroll
    for (int i = 0; i < 4; ++i) {
        int grow = row0 + r0 + i;
        if (grow >= NN) break;
        __half2* yp = (__half2*)&Yh[(size_t)grow * HID + c0];
        yp[0] = __floats2half2_rn(acc[i][0], acc[i][1]);
        yp[1] = __floats2half2_rn(acc[i][2], acc[i][3]);
        yp[2] = __floats2half2_rn(acc[i][4], acc[i][5]);
    }
}

// ---------------- B1: per-bucket degree count -> off (+dis), zero global atomics ----------
__global__ __launch_bounds__(256) void k_B1(const unsigned* __restrict__ tmp,
                                            const int* __restrict__ boff,
                                            int* __restrict__ off, float* __restrict__ dis) {
    __shared__ int cnt[BK_SIZE];
    __shared__ int psum[256];
    const int t = threadIdx.x;
    const int b = blockIdx.x;
    const int nb = b << BK_SHIFT;
    const int rbeg = boff[b], rend = boff[b + 1];
    cnt[t] = 0; cnt[t + 256] = 0;
    __syncthreads();
    for (int e = rbeg + t; e < rend; e += 256) {
        unsigned u = tmp[e];
        atomicAdd(&cnt[u >> 17], 1);
    }
    __syncthreads();
    int c0 = cnt[2 * t], c1 = cnt[2 * t + 1];
    int pairSum = c0 + c1;
    psum[t] = pairSum;
    __syncthreads();
    for (int ofs = 1; ofs < 256; ofs <<= 1) {
        int v = (t >= ofs) ? psum[t - ofs] : 0;
        __syncthreads();
        psum[t] += v;
        __syncthreads();
    }
    int pairExcl = psum[t] - pairSum;
    int node0 = nb + 2 * t, node1 = node0 + 1;
    if (node0 < NN) {
        off[node0] = rbeg + pairExcl;
        dis[node0] = rsqrtf((float)(c0 + 1));
    }
    if (node1 < NN) {
        off[node1] = rbeg + pairExcl + c0;
        dis[node1] = rsqrtf((float)(c1 + 1));
    }
    if (b == NBK - 1 && t == 0) off[NN] = rend;   // = NE
}

// ---------------- B2: per-bucket scatter into final CSR {src, w} ----------------
__global__ __launch_bounds__(256) void k_B2(const unsigned* __restrict__ tmp,
                                            const int* __restrict__ boff,
                                            const int* __restrict__ off,
                                            const float* __restrict__ dis,
                                            int2* __restrict__ ssrcw) {
    __shared__ int cnt[BK_SIZE];
    const int tid = threadIdx.x;
    const int b = blockIdx.x;
    const int nb = b << BK_SHIFT;
    const int rbeg = boff[b], rend = boff[b + 1];
    cnt[tid] = 0; cnt[tid + 256] = 0;
    __syncthreads();
    for (int e = rbeg + tid; e < rend; e += 256) {
        unsigned u = tmp[e];
        int s = (int)(u & 0x1FFFFu);
        int dl = (int)(u >> 17);
        int d = nb + dl;
        int pos = off[d] + atomicAdd(&cnt[dl], 1);
        float w = dis[s] * dis[d];
        ssrcw[pos] = make_int2(s, __float_as_int(w));
    }
}

// ---------------- GEMM2 (MFMA fp16, standalone; layout HW-validated round 10) ----------------
__global__ __launch_bounds__(256) void k_gemm2(const __half* __restrict__ Xh,
                                               const __half* __restrict__ W2frag,
                                               __half* __restrict__ Yh) {
    __shared__ __half w2s[9216];
    const int tid = threadIdx.x;
    {
        half8* d8 = (half8*)w2s;
        const half8* s8 = (const half8*)W2frag;
        for (int i = tid; i < 1152; i += 256) d8[i] = s8[i];
    }
    __syncthreads();
    const int w = tid >> 6;
    const int l = tid & 63;
    const int row0 = blockIdx.x * 64 + w * 16;
    int arow = row0 + (l & 15);
    if (arow >= NN) arow = NN - 1;
    f32x4 acc[6] = {};
#pragma unroll
    for (int kc = 0; kc < 3; ++kc) {
        half8 a = *(const half8*)&Xh[(size_t)arow * HID + kc * 32 + ((l >> 4) << 3)];
#pragma unroll
        for (int ct = 0; ct < 6; ++ct) {
            half8 b = *(const half8*)&w2s[((kc * 6 + ct) * 64 + l) * 8];
            acc[ct] = __builtin_amdgcn_mfma_f32_16x16x32_f16(a, b, acc[ct], 0, 0, 0);
        }
    }
    const int orow = row0 + ((l >> 4) << 2);
    const int col = l & 15;
#pragma unroll
    for (int ct = 0; ct < 6; ++ct)
#pragma unroll
        for (int i = 0; i < 4; ++i) {
            int r = orow + i;
            if (r < NN) Yh[(size_t)r * HID + ct * 16 + col] = __float2half(acc[ct][i]);
        }
}

// ---------------- fused GCN aggregation + node-logit partial (16 lanes/dst, half2) ------
template <int PHASE>
__global__ __launch_bounds__(256) void k_agg(const __half* __restrict__ Ah,
                                             const int2* __restrict__ ssrcw,
                                             const int* __restrict__ off,
                                             const float* __restrict__ dis,
                                             const float* __restrict__ bias,
                                             const float* __restrict__ Wn,
                                             const float* __restrict__ bn,
                                             __half* __restrict__ outh,
                                             float* __restrict__ nodeOut) {
    int gid = blockIdx.x * blockDim.x + threadIdx.x;
    int d = gid >> 4;
    int t = gid & 15;
    if (d >= NN) return;
    const int beg = off[d], end = off[d + 1];
    const float dd = dis[d];
    const __half2* ad2 = (const __half2*)(Ah + (size_t)d * HID);
    float2 s0 = __half22float2(ad2[t]);
    float2 s1 = __half22float2(ad2[t + 16]);
    float2 s2 = __half22float2(ad2[t + 32]);
    const float dd2 = dd * dd;
    float a0x = s0.x * dd2, a0y = s0.y * dd2;
    float a1x = s1.x * dd2, a1y = s1.y * dd2;
    float a2x = s2.x * dd2, a2y = s2.y * dd2;
    int j = beg;
    for (; j + 7 < end; j += 8) {
        int2 e[8];
#pragma unroll
        for (int q = 0; q < 8; ++q) e[q] = ssrcw[j + q];
        float w[8];
        const __half2* ap[8];
#pragma unroll
        for (int q = 0; q < 8; ++q) {
            w[q] = __int_as_float(e[q].y);
            ap[q] = (const __half2*)(Ah + (size_t)e[q].x * HID);
        }
        __half2 g0[8], g1[8], g2[8];
#pragma unroll
        for (int q = 0; q < 8; ++q) {
            g0[q] = ap[q][t];
            g1[q] = ap[q][t + 16];
            g2[q] = ap[q][t + 32];
        }
#pragma unroll
        for (int q = 0; q < 8; ++q) {
            float2 f0 = __half22float2(g0[q]);
            float2 f1 = __half22float2(g1[q]);
            float2 f2 = __half22float2(g2[q]);
            a0x += f0.x * w[q]; a0y += f0.y * w[q];
            a1x += f1.x * w[q]; a1y += f1.y * w[q];
            a2x += f2.x * w[q]; a2y += f2.y * w[q];
        }
    }
    for (; j < end; ++j) {
        int2 e0 = ssrcw[j];
        float w0 = __int_as_float(e0.y);
        const __half2* a0 = (const __half2*)(Ah + (size_t)e0.x * HID);
        float2 f0 = __half22float2(a0[t]);
        float2 f1 = __half22float2(a0[t + 16]);
        float2 f2 = __half22float2(a0[t + 32]);
        a0x += f0.x * w0; a0y += f0.y * w0;
        a1x += f1.x * w0; a1y += f1.y * w0;
        a2x += f2.x * w0; a2y += f2.y * w0;
    }
    const float2* b2p = (const float2*)bias;
    float2 b0 = b2p[t], b1 = b2p[t + 16], b2 = b2p[t + 32];
    float h0x = fmaxf(a0x + b0.x, 0.f), h0y = fmaxf(a0y + b0.y, 0.f);
    float h1x = fmaxf(a1x + b1.x, 0.f), h1y = fmaxf(a1y + b1.y, 0.f);
    float h2x = fmaxf(a2x + b2.x, 0.f), h2y = fmaxf(a2y + b2.y, 0.f);
    __half2* o2 = (__half2*)(outh + (size_t)d * HID);
    o2[t]      = __floats2half2_rn(h0x, h0y);
    o2[t + 16] = __floats2half2_rn(h1x, h1y);
    o2[t + 32] = __floats2half2_rn(h2x, h2y);

    const int woff = (PHASE == 1) ? 0 : 96;
    const float2* wn2 = (const float2*)(Wn + woff);
    float2 w0v = wn2[t], w1v = wn2[t + 16], w2v = wn2[t + 32];
    float partial = h0x * w0v.x + h0y * w0v.y + h1x * w1v.x + h1y * w1v.y +
                    h2x * w2v.x + h2y * w2v.y;
#pragma unroll
    for (int m = 8; m; m >>= 1) partial += __shfl_down(partial, m, 16);
    if (t == 0) {
        if (PHASE == 1) nodeOut[d] = partial + bn[0];
        else            nodeOut[d] += partial;
    }
}

// ---------------- graph pooling + graph head (fp16 H inputs) ----------------
__global__ __launch_bounds__(768) void k_pool(const __half* __restrict__ h1,
                                              const __half* __restrict__ h2,
                                              const int* __restrict__ batch,
                                              const float* __restrict__ Wg,
                                              const float* __restrict__ bg,
                                              float* __restrict__ out) {
    int g = blockIdx.x;
    int tid = threadIdx.x;       // 0..767
    int way = tid / 192;         // 0..3
    int f = tid - way * 192;     // 0..191

    int lo = 0, hi = NN;
    while (lo < hi) { int mid = (lo + hi) >> 1; if (batch[mid] < g) lo = mid + 1; else hi = mid; }
    int start = lo;
    hi = NN;
    while (lo < hi) { int mid = (lo + hi) >> 1; if (batch[mid] < g + 1) lo = mid + 1; else hi = mid; }
    int end = lo;

    const __half* hsrc = (f < HID) ? h1 : h2;
    int ff = (f < HID) ? f : f - HID;
    float sum = 0.f, mx = 0.f;  // h >= 0 post-relu
    for (int n = start + way; n < end; n += 4) {
        float v = __half2float(hsrc[(size_t)n * HID + ff]);
        sum += v;
        mx = fmaxf(mx, v);
    }
    __shared__ float rsum[4][192];
    __shared__ float rmax[4][192];
    rsum[way][f] = sum;
    rmax[way][f] = mx;
    __syncthreads();
    if (way == 0) {
        sum = rsum[0][f] + rsum[1][f] + rsum[2][f] + rsum[3][f];
        mx = fmaxf(fmaxf(rmax[0][f], rmax[1][f]), fmaxf(rmax[2][f], rmax[3][f]));
        float cnt = (float)(end - start);
        float mean = sum / fmaxf(cnt, 1.0f);
        rsum[0][f] = mean * Wg[f] + mx * Wg[192 + f];
    }
    __syncthreads();
    if (tid < 64) {
        float acc = rsum[0][tid] + rsum[0][tid + 64] + rsum[0][tid + 128];
#pragma unroll
        for (int m = 32; m; m >>= 1) acc += __shfl_down(acc, m, 64);
        if (tid == 0) out[g] = acc + bg[0];
    }
}

extern "C" void kernel_launch(void* const* d_in, const int* in_sizes, int n_in,
                              void* d_out, int out_size, void* d_ws, size_t ws_size,
                              hipStream_t stream) {
    const float* x    = (const float*)d_in[0];
    const int*   ei   = (const int*)d_in[1];
    const int*   srcp = ei;
    const int*   dstp = ei + NE;
    const int*   batch = (const int*)d_in[2];
    const float* W1 = (const float*)d_in[3];
    const float* b1 = (const float*)d_in[4];
    const float* W2 = (const float*)d_in[5];
    const float* b2 = (const float*)d_in[6];
    const float* Wn = (const float*)d_in[7];
    const float* bn = (const float*)d_in[8];
    const float* Wg = (const float*)d_in[9];
    const float* bg = (const float*)d_in[10];
    float* out = (float*)d_out;

    char* p = (char*)d_ws;
    auto alloc = [&](size_t bytes) {
        char* r = p;
        p += (bytes + 255) & ~(size_t)255;
        return (void*)r;
    };
    float*    dis    = (float*)alloc(NN * 4);
    int*      off    = (int*)alloc((NN + 1) * 4);
    int*      boff   = (int*)alloc((NBK + 1) * 4);
    int*      histAB = (int*)alloc((size_t)A_BLOCKS * NBK * 4);
    unsigned* tmp    = (unsigned*)alloc((size_t)NE * 4);
    int2*     ssrcw  = (int2*)alloc((size_t)NE * 8);
    __half*   Ah     = (__half*)alloc((size_t)NN * HID * 2);   // hw buffer (both convs)
    __half*   H1h    = (__half*)alloc((size_t)NN * HID * 2);
    __half*   H2h    = (__half*)alloc((size_t)NN * HID * 2);
    __half*   W2frag = (__half*)alloc(9216 * 2);

    const int TPB = 256;

    // CSR build: [A1 ∥ pack] ; scanS ; [A3 ∥ gemm1] ; B1 ; B2
    k_pack_a1<<<A_BLOCKS + 5, TPB, 0, stream>>>(dstp, histAB, W2, W2frag);
    k_scanS<<<1, 256, 0, stream>>>(histAB, boff);
    k_gemm1_a3<<<A_BLOCKS + GEMM1_BLOCKS, 256, 0, stream>>>(
        x, W1, Ah, srcp, dstp, boff, histAB, tmp);
    k_B1<<<NBK, 256, 0, stream>>>(tmp, boff, off, dis);
    k_B2<<<NBK, 256, 0, stream>>>(tmp, boff, off, dis, ssrcw);

    const int aggThreads = NN * 16;
    float* nodeOut = out + NG;

    // conv1 aggregate (16-lane half2): H1h ; nodeOut partial 1
    k_agg<1><<<(aggThreads + TPB - 1) / TPB, TPB, 0, stream>>>(Ah, ssrcw, off, dis, b1, Wn, bn, H1h, nodeOut);

    // conv2 transform (MFMA, standalone)
    k_gemm2<<<G2_BLOCKS, 256, 0, stream>>>(H1h, W2frag, Ah);

    // conv2 aggregate: H2h ; nodeOut partial 2
    k_agg<2><<<(aggThreads + TPB - 1) / TPB, TPB, 0, stream>>>(Ah, ssrcw, off, dis, b2, Wn, bn, H2h, nodeOut);

    // pooling + graph head
    k_pool<<<NG, 768, 0, stream>>>(H1h, H2h, batch, Wg, bg, out);
}

// Round 15
// 259.481 us; speedup vs baseline: 1.2850x; 1.0086x over previous
//
#include <hip/hip_runtime.h>
#include <hip/hip_fp16.h>

#define NN 100000      // nodes
#define NE 1600000     // edges
#define INC 128        // in channels
#define HID 96         // hidden
#define NG 512         // graphs

#define GEMM1_BLOCKS 1563        // ceil(NN/64)
#define G2_BLOCKS 1563           // ceil(NN/64) for MFMA gemm2

#define BK_SHIFT 9
#define BK_SIZE 512
#define NBK 196                  // ceil(NN/512)
#define A_EPB 16384              // edges per A-pass block
#define A_BLOCKS 98              // ceil(NE/16384)

typedef _Float16 half8 __attribute__((ext_vector_type(8)));
typedef float f32x4 __attribute__((ext_vector_type(4)));

// ---------------- FUSED: A1 (per-block bucket histogram) ∥ W1+W2 frag pack ----------------
// Wfrag[((kc*6+ct)*64+l)*8+i] = W[kc*32 + (l>>4)*8 + i][ct*16 + (l&15)]
__global__ __launch_bounds__(256) void k_pack_a1(const int* __restrict__ dst,
                                                 int* __restrict__ histAB,
                                                 const float* __restrict__ W1,
                                                 const float* __restrict__ W2,
                                                 __half* __restrict__ W1frag,
                                                 __half* __restrict__ W2frag) {
    const int tid = threadIdx.x;
    if (blockIdx.x < A_BLOCKS) {
        __shared__ int cnt[NBK];
        int ab = blockIdx.x;
        for (int i = tid; i < NBK; i += 256) cnt[i] = 0;
        __syncthreads();
        int e0 = ab * A_EPB;
#pragma unroll 4
        for (int q = 0; q < A_EPB / 256; ++q) {
            int e = e0 + q * 256 + tid;
            if (e < NE) atomicAdd(&cnt[dst[e] >> BK_SHIFT], 1);
        }
        __syncthreads();
        for (int i = tid; i < NBK; i += 256) histAB[ab * NBK + i] = cnt[i];
        return;
    }
    int p = (blockIdx.x - A_BLOCKS) * 256 + tid;
    if (p < 1536) {
        // ---- W1 pack: kc in [0,4) ----
        int kc = p / 384;
        int rem = p - kc * 384;
        int ct = rem >> 6;
        int l = rem & 63;
#pragma unroll
        for (int i = 0; i < 8; ++i) {
            int k = kc * 32 + ((l >> 4) << 3) + i;
            int c = ct * 16 + (l & 15);
            W1frag[p * 8 + i] = __float2half(W1[k * HID + c]);
        }
    } else {
        int q = p - 1536;
        if (q >= 1152) return;
        // ---- W2 pack: kc in [0,3) ----
        int kc = q / 384;
        int rem = q - kc * 384;
        int ct = rem >> 6;
        int l = rem & 63;
#pragma unroll
        for (int i = 0; i < 8; ++i) {
            int k = kc * 32 + ((l >> 4) << 3) + i;
            int c = ct * 16 + (l & 15);
            W2frag[q * 8 + i] = __float2half(W2[k * HID + c]);
        }
    }
}

// ---------------- scanS: column prefix of histAB + bucket prefix -> boff ----------------
__global__ __launch_bounds__(256) void k_scanS(int* __restrict__ histAB, int* __restrict__ boff) {
    __shared__ int tot[256];
    int t = threadIdx.x;
    int run = 0;
    if (t < NBK) {
        for (int blk = 0; blk < A_BLOCKS; ++blk) {
            int idx = blk * NBK + t;
            int v = histAB[idx];
            histAB[idx] = run;   // exclusive prefix along blocks
            run += v;
        }
    }
    tot[t] = (t < NBK) ? run : 0;
    __syncthreads();
    for (int ofs = 1; ofs < 256; ofs <<= 1) {
        int v = (t >= ofs) ? tot[t - ofs] : 0;
        __syncthreads();
        tot[t] += v;
        __syncthreads();
    }
    if (t == 0) boff[0] = 0;
    if (t < NBK) boff[t + 1] = tot[t];   // boff[NBK] = NE
}

// ---------------- FUSED: A3 (binned edge write) ∥ gemm1 (MFMA fp16) ----------------
// gemm1: Yh[N,96] = fp16( f32x[N,128] @ W1 ), A-frags cvt'd in-register from f32.
__global__ __launch_bounds__(256) void k_gemm1_a3(
        const float* __restrict__ X, const __half* __restrict__ W1frag,
        __half* __restrict__ Yh,
        const int* __restrict__ src, const int* __restrict__ dst,
        const int* __restrict__ boff, const int* __restrict__ histAB,
        unsigned* __restrict__ tmp) {
    __shared__ __half w1s[12288];   // 24.6 KB (A3 overlays base/lcnt here)
    const int tid = threadIdx.x;

    if (blockIdx.x < A_BLOCKS) {
        int* base = (int*)w1s;
        int* lcnt = base + NBK;
        int ab = blockIdx.x;
        for (int i = tid; i < NBK; i += 256) {
            base[i] = boff[i] + histAB[ab * NBK + i];
            lcnt[i] = 0;
        }
        __syncthreads();
        int e0 = ab * A_EPB;
#pragma unroll 4
        for (int q = 0; q < A_EPB / 256; ++q) {
            int e = e0 + q * 256 + tid;
            if (e < NE) {
                int d = dst[e];
                int bk = d >> BK_SHIFT;
                int lp = atomicAdd(&lcnt[bk], 1);
                tmp[base[bk] + lp] = (unsigned)src[e] | ((unsigned)(d & (BK_SIZE - 1)) << 17);
            }
        }
        return;
    }

    // ---- gemm1 MFMA body (K = 128, 4 steps) ----
    {
        half8* d8 = (half8*)w1s;
        const half8* s8 = (const half8*)W1frag;
        for (int i = tid; i < 1536; i += 256) d8[i] = s8[i];
    }
    __syncthreads();
    const int w = tid >> 6;          // wave 0..3
    const int l = tid & 63;          // lane
    const int row0 = (blockIdx.x - A_BLOCKS) * 64 + w * 16;
    int arow = row0 + (l & 15);
    if (arow >= NN) arow = NN - 1;   // clamp (stores guarded)
    f32x4 acc[6] = {};
#pragma unroll
    for (int kc = 0; kc < 4; ++kc) {
        const float* xp = &X[(size_t)arow * INC + kc * 32 + ((l >> 4) << 3)];
        float4 xa = *(const float4*)xp;
        float4 xb = *(const float4*)(xp + 4);
        half8 a;
        a[0] = (_Float16)xa.x; a[1] = (_Float16)xa.y;
        a[2] = (_Float16)xa.z; a[3] = (_Float16)xa.w;
        a[4] = (_Float16)xb.x; a[5] = (_Float16)xb.y;
        a[6] = (_Float16)xb.z; a[7] = (_Float16)xb.w;
#pragma unroll
        for (int ct = 0; ct < 6; ++ct) {
            half8 b = *(const half8*)&w1s[((kc * 6 + ct) * 64 + l) * 8];
            acc[ct] = __builtin_amdgcn_mfma_f32_16x16x32_f16(a, b, acc[ct], 0, 0, 0);
        }
    }
    // C layout (HW-validated round 10): col = lane&15, row = (lane>>4)*4 + i
    const int orow = row0 + ((l >> 4) << 2);
    const int col = l & 15;
#pragma unroll
    for (int ct = 0; ct < 6; ++ct)
#pragma unroll
        for (int i = 0; i < 4; ++i) {
            int r = orow + i;
            if (r < NN) Yh[(size_t)r * HID + ct * 16 + col] = __float2half(acc[ct][i]);
        }
}

// ---------------- B1: per-bucket degree count -> off (+dis), zero global atomics ----------
__global__ __launch_bounds__(256) void k_B1(const unsigned* __restrict__ tmp,
                                            const int* __restrict__ boff,
                                            int* __restrict__ off, float* __restrict__ dis) {
    __shared__ int cnt[BK_SIZE];
    __shared__ int psum[256];
    const int t = threadIdx.x;
    const int b = blockIdx.x;
    const int nb = b << BK_SHIFT;
    const int rbeg = boff[b], rend = boff[b + 1];
    cnt[t] = 0; cnt[t + 256] = 0;
    __syncthreads();
    for (int e = rbeg + t; e < rend; e += 256) {
        unsigned u = tmp[e];
        atomicAdd(&cnt[u >> 17], 1);
    }
    __syncthreads();
    int c0 = cnt[2 * t], c1 = cnt[2 * t + 1];
    int pairSum = c0 + c1;
    psum[t] = pairSum;
    __syncthreads();
    for (int ofs = 1; ofs < 256; ofs <<= 1) {
        int v = (t >= ofs) ? psum[t - ofs] : 0;
        __syncthreads();
        psum[t] += v;
        __syncthreads();
    }
    int pairExcl = psum[t] - pairSum;
    int node0 = nb + 2 * t, node1 = node0 + 1;
    if (node0 < NN) {
        off[node0] = rbeg + pairExcl;
        dis[node0] = rsqrtf((float)(c0 + 1));
    }
    if (node1 < NN) {
        off[node1] = rbeg + pairExcl + c0;
        dis[node1] = rsqrtf((float)(c1 + 1));
    }
    if (b == NBK - 1 && t == 0) off[NN] = rend;   // = NE
}

// ---------------- B2: per-bucket scatter into final CSR {src, w} ----------------
__global__ __launch_bounds__(256) void k_B2(const unsigned* __restrict__ tmp,
                                            const int* __restrict__ boff,
                                            const int* __restrict__ off,
                                            const float* __restrict__ dis,
                                            int2* __restrict__ ssrcw) {
    __shared__ int cnt[BK_SIZE];
    const int tid = threadIdx.x;
    const int b = blockIdx.x;
    const int nb = b << BK_SHIFT;
    const int rbeg = boff[b], rend = boff[b + 1];
    cnt[tid] = 0; cnt[tid + 256] = 0;
    __syncthreads();
    for (int e = rbeg + tid; e < rend; e += 256) {
        unsigned u = tmp[e];
        int s = (int)(u & 0x1FFFFu);
        int dl = (int)(u >> 17);
        int d = nb + dl;
        int pos = off[d] + atomicAdd(&cnt[dl], 1);
        float w = dis[s] * dis[d];
        ssrcw[pos] = make_int2(s, __float_as_int(w));
    }
}

// ---------------- GEMM2 (MFMA fp16, standalone; layout HW-validated round 10) ----------------
__global__ __launch_bounds__(256) void k_gemm2(const __half* __restrict__ Xh,
                                               const __half* __restrict__ W2frag,
                                               __half* __restrict__ Yh) {
    __shared__ __half w2s[9216];
    const int tid = threadIdx.x;
    {
        half8* d8 = (half8*)w2s;
        const half8* s8 = (const half8*)W2frag;
        for (int i = tid; i < 1152; i += 256) d8[i] = s8[i];
    }
    __syncthreads();
    const int w = tid >> 6;
    const int l = tid & 63;
    const int row0 = blockIdx.x * 64 + w * 16;
    int arow = row0 + (l & 15);
    if (arow >= NN) arow = NN - 1;
    f32x4 acc[6] = {};
#pragma unroll
    for (int kc = 0; kc < 3; ++kc) {
        half8 a = *(const half8*)&Xh[(size_t)arow * HID + kc * 32 + ((l >> 4) << 3)];
#pragma unroll
        for (int ct = 0; ct < 6; ++ct) {
            half8 b = *(const half8*)&w2s[((kc * 6 + ct) * 64 + l) * 8];
            acc[ct] = __builtin_amdgcn_mfma_f32_16x16x32_f16(a, b, acc[ct], 0, 0, 0);
        }
    }
    const int orow = row0 + ((l >> 4) << 2);
    const int col = l & 15;
#pragma unroll
    for (int ct = 0; ct < 6; ++ct)
#pragma unroll
        for (int i = 0; i < 4; ++i) {
            int r = orow + i;
            if (r < NN) Yh[(size_t)r * HID + ct * 16 + col] = __float2half(acc[ct][i]);
        }
}

// ---------------- fused GCN aggregation + node-logit partial (16 lanes/dst, half2) ------
template <int PHASE>
__global__ __launch_bounds__(256) void k_agg(const __half* __restrict__ Ah,
                                             const int2* __restrict__ ssrcw,
                                             const int* __restrict__ off,
                                             const float* __restrict__ dis,
                                             const float* __restrict__ bias,
                                             const float* __restrict__ Wn,
                                             const float* __restrict__ bn,
                                             __half* __restrict__ outh,
                                             float* __restrict__ nodeOut) {
    int gid = blockIdx.x * blockDim.x + threadIdx.x;
    int d = gid >> 4;
    int t = gid & 15;
    if (d >= NN) return;
    const int beg = off[d], end = off[d + 1];
    const float dd = dis[d];
    const __half2* ad2 = (const __half2*)(Ah + (size_t)d * HID);
    float2 s0 = __half22float2(ad2[t]);
    float2 s1 = __half22float2(ad2[t + 16]);
    float2 s2 = __half22float2(ad2[t + 32]);
    const float dd2 = dd * dd;
    float a0x = s0.x * dd2, a0y = s0.y * dd2;
    float a1x = s1.x * dd2, a1y = s1.y * dd2;
    float a2x = s2.x * dd2, a2y = s2.y * dd2;
    int j = beg;
    for (; j + 7 < end; j += 8) {
        int2 e[8];
#pragma unroll
        for (int q = 0; q < 8; ++q) e[q] = ssrcw[j + q];
        float w[8];
        const __half2* ap[8];
#pragma unroll
        for (int q = 0; q < 8; ++q) {
            w[q] = __int_as_float(e[q].y);
            ap[q] = (const __half2*)(Ah + (size_t)e[q].x * HID);
        }
        __half2 g0[8], g1[8], g2[8];
#pragma unroll
        for (int q = 0; q < 8; ++q) {
            g0[q] = ap[q][t];
            g1[q] = ap[q][t + 16];
            g2[q] = ap[q][t + 32];
        }
#pragma unroll
        for (int q = 0; q < 8; ++q) {
            float2 f0 = __half22float2(g0[q]);
            float2 f1 = __half22float2(g1[q]);
            float2 f2 = __half22float2(g2[q]);
            a0x += f0.x * w[q]; a0y += f0.y * w[q];
            a1x += f1.x * w[q]; a1y += f1.y * w[q];
            a2x += f2.x * w[q]; a2y += f2.y * w[q];
        }
    }
    for (; j < end; ++j) {
        int2 e0 = ssrcw[j];
        float w0 = __int_as_float(e0.y);
        const __half2* a0 = (const __half2*)(Ah + (size_t)e0.x * HID);
        float2 f0 = __half22float2(a0[t]);
        float2 f1 = __half22float2(a0[t + 16]);
        float2 f2 = __half22float2(a0[t + 32]);
        a0x += f0.x * w0; a0y += f0.y * w0;
        a1x += f1.x * w0; a1y += f1.y * w0;
        a2x += f2.x * w0; a2y += f2.y * w0;
    }
    const float2* b2p = (const float2*)bias;
    float2 b0 = b2p[t], b1 = b2p[t + 16], b2 = b2p[t + 32];
    float h0x = fmaxf(a0x + b0.x, 0.f), h0y = fmaxf(a0y + b0.y, 0.f);
    float h1x = fmaxf(a1x + b1.x, 0.f), h1y = fmaxf(a1y + b1.y, 0.f);
    float h2x = fmaxf(a2x + b2.x, 0.f), h2y = fmaxf(a2y + b2.y, 0.f);
    __half2* o2 = (__half2*)(outh + (size_t)d * HID);
    o2[t]      = __floats2half2_rn(h0x, h0y);
    o2[t + 16] = __floats2half2_rn(h1x, h1y);
    o2[t + 32] = __floats2half2_rn(h2x, h2y);

    const int woff = (PHASE == 1) ? 0 : 96;
    const float2* wn2 = (const float2*)(Wn + woff);
    float2 w0v = wn2[t], w1v = wn2[t + 16], w2v = wn2[t + 32];
    float partial = h0x * w0v.x + h0y * w0v.y + h1x * w1v.x + h1y * w1v.y +
                    h2x * w2v.x + h2y * w2v.y;
#pragma unroll
    for (int m = 8; m; m >>= 1) partial += __shfl_down(partial, m, 16);
    if (t == 0) {
        if (PHASE == 1) nodeOut[d] = partial + bn[0];
        else            nodeOut[d] += partial;
    }
}

// ---------------- graph pooling + graph head (fp16 H inputs) ----------------
__global__ __launch_bounds__(768) void k_pool(const __half* __restrict__ h1,
                                              const __half* __restrict__ h2,
                                              const int* __restrict__ batch,
                                              const float* __restrict__ Wg,
                                              const float* __restrict__ bg,
                                              float* __restrict__ out) {
    int g = blockIdx.x;
    int tid = threadIdx.x;       // 0..767
    int way = tid / 192;         // 0..3
    int f = tid - way * 192;     // 0..191

    int lo = 0, hi = NN;
    while (lo < hi) { int mid = (lo + hi) >> 1; if (batch[mid] < g) lo = mid + 1; else hi = mid; }
    int start = lo;
    hi = NN;
    while (lo < hi) { int mid = (lo + hi) >> 1; if (batch[mid] < g + 1) lo = mid + 1; else hi = mid; }
    int end = lo;

    const __half* hsrc = (f < HID) ? h1 : h2;
    int ff = (f < HID) ? f : f - HID;
    float sum = 0.f, mx = 0.f;  // h >= 0 post-relu
    for (int n = start + way; n < end; n += 4) {
        float v = __half2float(hsrc[(size_t)n * HID + ff]);
        sum += v;
        mx = fmaxf(mx, v);
    }
    __shared__ float rsum[4][192];
    __shared__ float rmax[4][192];
    rsum[way][f] = sum;
    rmax[way][f] = mx;
    __syncthreads();
    if (way == 0) {
        sum = rsum[0][f] + rsum[1][f] + rsum[2][f] + rsum[3][f];
        mx = fmaxf(fmaxf(rmax[0][f], rmax[1][f]), fmaxf(rmax[2][f], rmax[3][f]));
        float cnt = (float)(end - start);
        float mean = sum / fmaxf(cnt, 1.0f);
        rsum[0][f] = mean * Wg[f] + mx * Wg[192 + f];
    }
    __syncthreads();
    if (tid < 64) {
        float acc = rsum[0][tid] + rsum[0][tid + 64] + rsum[0][tid + 128];
#pragma unroll
        for (int m = 32; m; m >>= 1) acc += __shfl_down(acc, m, 64);
        if (tid == 0) out[g] = acc + bg[0];
    }
}

extern "C" void kernel_launch(void* const* d_in, const int* in_sizes, int n_in,
                              void* d_out, int out_size, void* d_ws, size_t ws_size,
                              hipStream_t stream) {
    const float* x    = (const float*)d_in[0];
    const int*   ei   = (const int*)d_in[1];
    const int*   srcp = ei;
    const int*   dstp = ei + NE;
    const int*   batch = (const int*)d_in[2];
    const float* W1 = (const float*)d_in[3];
    const float* b1 = (const float*)d_in[4];
    const float* W2 = (const float*)d_in[5];
    const float* b2 = (const float*)d_in[6];
    const float* Wn = (const float*)d_in[7];
    const float* bn = (const float*)d_in[8];
    const float* Wg = (const float*)d_in[9];
    const float* bg = (const float*)d_in[10];
    float* out = (float*)d_out;

    char* p = (char*)d_ws;
    auto alloc = [&](size_t bytes) {
        char* r = p;
        p += (bytes + 255) & ~(size_t)255;
        return (void*)r;
    };
    float*    dis    = (float*)alloc(NN * 4);
    int*      off    = (int*)alloc((NN + 1) * 4);
    int*      boff   = (int*)alloc((NBK + 1) * 4);
    int*      histAB = (int*)alloc((size_t)A_BLOCKS * NBK * 4);
    unsigned* tmp    = (unsigned*)alloc((size_t)NE * 4);
    int2*     ssrcw  = (int2*)alloc((size_t)NE * 8);
    __half*   Ah     = (__half*)alloc((size_t)NN * HID * 2);   // hw buffer (both convs)
    __half*   H1h    = (__half*)alloc((size_t)NN * HID * 2);
    __half*   H2h    = (__half*)alloc((size_t)NN * HID * 2);
    __half*   W1frag = (__half*)alloc(12288 * 2);
    __half*   W2frag = (__half*)alloc(9216 * 2);

    const int TPB = 256;

    // CSR build + weight pack: [A1 ∥ pack] ; scanS ; [A3 ∥ gemm1-MFMA] ; B1 ; B2
    k_pack_a1<<<A_BLOCKS + 11, TPB, 0, stream>>>(dstp, histAB, W1, W2, W1frag, W2frag);
    k_scanS<<<1, 256, 0, stream>>>(histAB, boff);
    k_gemm1_a3<<<A_BLOCKS + GEMM1_BLOCKS, 256, 0, stream>>>(
        x, W1frag, Ah, srcp, dstp, boff, histAB, tmp);
    k_B1<<<NBK, 256, 0, stream>>>(tmp, boff, off, dis);
    k_B2<<<NBK, 256, 0, stream>>>(tmp, boff, off, dis, ssrcw);

    const int aggThreads = NN * 16;
    float* nodeOut = out + NG;

    // conv1 aggregate (16-lane half2): H1h ; nodeOut partial 1
    k_agg<1><<<(aggThreads + TPB - 1) / TPB, TPB, 0, stream>>>(Ah, ssrcw, off, dis, b1, Wn, bn, H1h, nodeOut);

    // conv2 transform (MFMA, standalone)
    k_gemm2<<<G2_BLOCKS, 256, 0, stream>>>(H1h, W2frag, Ah);

    // conv2 aggregate: H2h ; nodeOut partial 2
    k_agg<2><<<(aggThreads + TPB - 1) / TPB, TPB, 0, stream>>>(Ah, ssrcw, off, dis, b2, Wn, bn, H2h, nodeOut);

    // pooling + graph head
    k_pool<<<NG, 768, 0, stream>>>(H1h, H2h, batch, Wg, bg, out);
}

// Round 16
// 248.157 us; speedup vs baseline: 1.3436x; 1.0456x over previous
//
#include <hip/hip_runtime.h>
#include <hip/hip_fp16.h>

#define NN 100000      // nodes
#define NE 1600000     // edges
#define INC 128        // in channels
#define HID 96         // hidden
#define NG 512         // graphs

#define GEMM1_BLOCKS 1563        // ceil(NN/64)
#define G2_BLOCKS 1563           // ceil(NN/64) for MFMA gemm2

#define BK_SHIFT 9
#define BK_SIZE 512
#define NBK 196                  // ceil(NN/512)
#define A_EPB 4096               // edges per A-pass block
#define A_BLOCKS 391             // ceil(NE/4096)

typedef _Float16 half8 __attribute__((ext_vector_type(8)));
typedef float f32x4 __attribute__((ext_vector_type(4)));

// ---------------- FUSED: A1 (per-block bucket histogram) ∥ W1+W2 frag pack ----------------
// Wfrag[((kc*6+ct)*64+l)*8+i] = W[kc*32 + (l>>4)*8 + i][ct*16 + (l&15)]
__global__ __launch_bounds__(256) void k_pack_a1(const int* __restrict__ dst,
                                                 int* __restrict__ histAB,
                                                 const float* __restrict__ W1,
                                                 const float* __restrict__ W2,
                                                 __half* __restrict__ W1frag,
                                                 __half* __restrict__ W2frag) {
    const int tid = threadIdx.x;
    if (blockIdx.x < A_BLOCKS) {
        __shared__ int cnt[NBK];
        int ab = blockIdx.x;
        for (int i = tid; i < NBK; i += 256) cnt[i] = 0;
        __syncthreads();
        int e0 = ab * A_EPB;
#pragma unroll 4
        for (int q = 0; q < A_EPB / 256; ++q) {
            int e = e0 + q * 256 + tid;
            if (e < NE) atomicAdd(&cnt[dst[e] >> BK_SHIFT], 1);
        }
        __syncthreads();
        for (int i = tid; i < NBK; i += 256) histAB[ab * NBK + i] = cnt[i];
        return;
    }
    int p = (blockIdx.x - A_BLOCKS) * 256 + tid;
    if (p < 1536) {
        // ---- W1 pack: kc in [0,4) ----
        int kc = p / 384;
        int rem = p - kc * 384;
        int ct = rem >> 6;
        int l = rem & 63;
#pragma unroll
        for (int i = 0; i < 8; ++i) {
            int k = kc * 32 + ((l >> 4) << 3) + i;
            int c = ct * 16 + (l & 15);
            W1frag[p * 8 + i] = __float2half(W1[k * HID + c]);
        }
    } else {
        int q = p - 1536;
        if (q >= 1152) return;
        // ---- W2 pack: kc in [0,3) ----
        int kc = q / 384;
        int rem = q - kc * 384;
        int ct = rem >> 6;
        int l = rem & 63;
#pragma unroll
        for (int i = 0; i < 8; ++i) {
            int k = kc * 32 + ((l >> 4) << 3) + i;
            int c = ct * 16 + (l & 15);
            W2frag[q * 8 + i] = __float2half(W2[k * HID + c]);
        }
    }
}

// ---------------- scanS: column prefix of histAB + bucket prefix -> boff ----------------
__global__ __launch_bounds__(256) void k_scanS(int* __restrict__ histAB, int* __restrict__ boff) {
    __shared__ int tot[256];
    int t = threadIdx.x;
    int run = 0;
    if (t < NBK) {
        for (int blk = 0; blk < A_BLOCKS; ++blk) {
            int idx = blk * NBK + t;
            int v = histAB[idx];
            histAB[idx] = run;   // exclusive prefix along blocks
            run += v;
        }
    }
    tot[t] = (t < NBK) ? run : 0;
    __syncthreads();
    for (int ofs = 1; ofs < 256; ofs <<= 1) {
        int v = (t >= ofs) ? tot[t - ofs] : 0;
        __syncthreads();
        tot[t] += v;
        __syncthreads();
    }
    if (t == 0) boff[0] = 0;
    if (t < NBK) boff[t + 1] = tot[t];   // boff[NBK] = NE
}

// ---------------- FUSED: A3 (binned edge write) ∥ gemm1 (MFMA fp16) ----------------
// gemm1: Yh[N,96] = fp16( f32x[N,128] @ W1 ), A-frags cvt'd in-register from f32.
__global__ __launch_bounds__(256) void k_gemm1_a3(
        const float* __restrict__ X, const __half* __restrict__ W1frag,
        __half* __restrict__ Yh,
        const int* __restrict__ src, const int* __restrict__ dst,
        const int* __restrict__ boff, const int* __restrict__ histAB,
        unsigned* __restrict__ tmp) {
    __shared__ __half w1s[12288];   // 24.6 KB (A3 overlays base/lcnt here)
    const int tid = threadIdx.x;

    if (blockIdx.x < A_BLOCKS) {
        int* base = (int*)w1s;
        int* lcnt = base + NBK;
        int ab = blockIdx.x;
        for (int i = tid; i < NBK; i += 256) {
            base[i] = boff[i] + histAB[ab * NBK + i];
            lcnt[i] = 0;
        }
        __syncthreads();
        int e0 = ab * A_EPB;
#pragma unroll 4
        for (int q = 0; q < A_EPB / 256; ++q) {
            int e = e0 + q * 256 + tid;
            if (e < NE) {
                int d = dst[e];
                int bk = d >> BK_SHIFT;
                int lp = atomicAdd(&lcnt[bk], 1);
                tmp[base[bk] + lp] = (unsigned)src[e] | ((unsigned)(d & (BK_SIZE - 1)) << 17);
            }
        }
        return;
    }

    // ---- gemm1 MFMA body (K = 128, 4 steps) ----
    {
        half8* d8 = (half8*)w1s;
        const half8* s8 = (const half8*)W1frag;
        for (int i = tid; i < 1536; i += 256) d8[i] = s8[i];
    }
    __syncthreads();
    const int w = tid >> 6;          // wave 0..3
    const int l = tid & 63;          // lane
    const int row0 = (blockIdx.x - A_BLOCKS) * 64 + w * 16;
    int arow = row0 + (l & 15);
    if (arow >= NN) arow = NN - 1;   // clamp (stores guarded)
    f32x4 acc[6] = {};
#pragma unroll
    for (int kc = 0; kc < 4; ++kc) {
        const float* xp = &X[(size_t)arow * INC + kc * 32 + ((l >> 4) << 3)];
        float4 xa = *(const float4*)xp;
        float4 xb = *(const float4*)(xp + 4);
        half8 a;
        a[0] = (_Float16)xa.x; a[1] = (_Float16)xa.y;
        a[2] = (_Float16)xa.z; a[3] = (_Float16)xa.w;
        a[4] = (_Float16)xb.x; a[5] = (_Float16)xb.y;
        a[6] = (_Float16)xb.z; a[7] = (_Float16)xb.w;
#pragma unroll
        for (int ct = 0; ct < 6; ++ct) {
            half8 b = *(const half8*)&w1s[((kc * 6 + ct) * 64 + l) * 8];
            acc[ct] = __builtin_amdgcn_mfma_f32_16x16x32_f16(a, b, acc[ct], 0, 0, 0);
        }
    }
    // C layout (HW-validated round 10): col = lane&15, row = (lane>>4)*4 + i
    const int orow = row0 + ((l >> 4) << 2);
    const int col = l & 15;
#pragma unroll
    for (int ct = 0; ct < 6; ++ct)
#pragma unroll
        for (int i = 0; i < 4; ++i) {
            int r = orow + i;
            if (r < NN) Yh[(size_t)r * HID + ct * 16 + col] = __float2half(acc[ct][i]);
        }
}

// ---------------- B1: per-bucket degree count -> off (+dis), zero global atomics ----------
__global__ __launch_bounds__(256) void k_B1(const unsigned* __restrict__ tmp,
                                            const int* __restrict__ boff,
                                            int* __restrict__ off, float* __restrict__ dis) {
    __shared__ int cnt[BK_SIZE];
    __shared__ int psum[256];
    const int t = threadIdx.x;
    const int b = blockIdx.x;
    const int nb = b << BK_SHIFT;
    const int rbeg = boff[b], rend = boff[b + 1];
    cnt[t] = 0; cnt[t + 256] = 0;
    __syncthreads();
    for (int e = rbeg + t; e < rend; e += 256) {
        unsigned u = tmp[e];
        atomicAdd(&cnt[u >> 17], 1);
    }
    __syncthreads();
    int c0 = cnt[2 * t], c1 = cnt[2 * t + 1];
    int pairSum = c0 + c1;
    psum[t] = pairSum;
    __syncthreads();
    for (int ofs = 1; ofs < 256; ofs <<= 1) {
        int v = (t >= ofs) ? psum[t - ofs] : 0;
        __syncthreads();
        psum[t] += v;
        __syncthreads();
    }
    int pairExcl = psum[t] - pairSum;
    int node0 = nb + 2 * t, node1 = node0 + 1;
    if (node0 < NN) {
        off[node0] = rbeg + pairExcl;
        dis[node0] = rsqrtf((float)(c0 + 1));
    }
    if (node1 < NN) {
        off[node1] = rbeg + pairExcl + c0;
        dis[node1] = rsqrtf((float)(c1 + 1));
    }
    if (b == NBK - 1 && t == 0) off[NN] = rend;   // = NE
}

// ---------------- B2: per-bucket scatter into final CSR {src, w} ----------------
__global__ __launch_bounds__(256) void k_B2(const unsigned* __restrict__ tmp,
                                            const int* __restrict__ boff,
                                            const int* __restrict__ off,
                                            const float* __restrict__ dis,
                                            int2* __restrict__ ssrcw) {
    __shared__ int cnt[BK_SIZE];
    const int tid = threadIdx.x;
    const int b = blockIdx.x;
    const int nb = b << BK_SHIFT;
    const int rbeg = boff[b], rend = boff[b + 1];
    cnt[tid] = 0; cnt[tid + 256] = 0;
    __syncthreads();
    for (int e = rbeg + tid; e < rend; e += 256) {
        unsigned u = tmp[e];
        int s = (int)(u & 0x1FFFFu);
        int dl = (int)(u >> 17);
        int d = nb + dl;
        int pos = off[d] + atomicAdd(&cnt[dl], 1);
        float w = dis[s] * dis[d];
        ssrcw[pos] = make_int2(s, __float_as_int(w));
    }
}

// ---------------- GEMM2 (MFMA fp16, standalone; layout HW-validated round 10) ----------------
__global__ __launch_bounds__(256) void k_gemm2(const __half* __restrict__ Xh,
                                               const __half* __restrict__ W2frag,
                                               __half* __restrict__ Yh) {
    __shared__ __half w2s[9216];
    const int tid = threadIdx.x;
    {
        half8* d8 = (half8*)w2s;
        const half8* s8 = (const half8*)W2frag;
        for (int i = tid; i < 1152; i += 256) d8[i] = s8[i];
    }
    __syncthreads();
    const int w = tid >> 6;
    const int l = tid & 63;
    const int row0 = blockIdx.x * 64 + w * 16;
    int arow = row0 + (l & 15);
    if (arow >= NN) arow = NN - 1;
    f32x4 acc[6] = {};
#pragma unroll
    for (int kc = 0; kc < 3; ++kc) {
        half8 a = *(const half8*)&Xh[(size_t)arow * HID + kc * 32 + ((l >> 4) << 3)];
#pragma unroll
        for (int ct = 0; ct < 6; ++ct) {
            half8 b = *(const half8*)&w2s[((kc * 6 + ct) * 64 + l) * 8];
            acc[ct] = __builtin_amdgcn_mfma_f32_16x16x32_f16(a, b, acc[ct], 0, 0, 0);
        }
    }
    const int orow = row0 + ((l >> 4) << 2);
    const int col = l & 15;
#pragma unroll
    for (int ct = 0; ct < 6; ++ct)
#pragma unroll
        for (int i = 0; i < 4; ++i) {
            int r = orow + i;
            if (r < NN) Yh[(size_t)r * HID + ct * 16 + col] = __float2half(acc[ct][i]);
        }
}

// ---------------- fused GCN aggregation + node-logit partial (16 lanes/dst, half2) ------
template <int PHASE>
__global__ __launch_bounds__(256) void k_agg(const __half* __restrict__ Ah,
                                             const int2* __restrict__ ssrcw,
                                             const int* __restrict__ off,
                                             const float* __restrict__ dis,
                                             const float* __restrict__ bias,
                                             const float* __restrict__ Wn,
                                             const float* __restrict__ bn,
                                             __half* __restrict__ outh,
                                             float* __restrict__ nodeOut) {
    int gid = blockIdx.x * blockDim.x + threadIdx.x;
    int d = gid >> 4;
    int t = gid & 15;
    if (d >= NN) return;
    const int beg = off[d], end = off[d + 1];
    const float dd = dis[d];
    const __half2* ad2 = (const __half2*)(Ah + (size_t)d * HID);
    float2 s0 = __half22float2(ad2[t]);
    float2 s1 = __half22float2(ad2[t + 16]);
    float2 s2 = __half22float2(ad2[t + 32]);
    const float dd2 = dd * dd;
    float a0x = s0.x * dd2, a0y = s0.y * dd2;
    float a1x = s1.x * dd2, a1y = s1.y * dd2;
    float a2x = s2.x * dd2, a2y = s2.y * dd2;
    int j = beg;
    for (; j + 7 < end; j += 8) {
        int2 e[8];
#pragma unroll
        for (int q = 0; q < 8; ++q) e[q] = ssrcw[j + q];
        float w[8];
        const __half2* ap[8];
#pragma unroll
        for (int q = 0; q < 8; ++q) {
            w[q] = __int_as_float(e[q].y);
            ap[q] = (const __half2*)(Ah + (size_t)e[q].x * HID);
        }
        __half2 g0[8], g1[8], g2[8];
#pragma unroll
        for (int q = 0; q < 8; ++q) {
            g0[q] = ap[q][t];
            g1[q] = ap[q][t + 16];
            g2[q] = ap[q][t + 32];
        }
#pragma unroll
        for (int q = 0; q < 8; ++q) {
            float2 f0 = __half22float2(g0[q]);
            float2 f1 = __half22float2(g1[q]);
            float2 f2 = __half22float2(g2[q]);
            a0x += f0.x * w[q]; a0y += f0.y * w[q];
            a1x += f1.x * w[q]; a1y += f1.y * w[q];
            a2x += f2.x * w[q]; a2y += f2.y * w[q];
        }
    }
    for (; j < end; ++j) {
        int2 e0 = ssrcw[j];
        float w0 = __int_as_float(e0.y);
        const __half2* a0 = (const __half2*)(Ah + (size_t)e0.x * HID);
        float2 f0 = __half22float2(a0[t]);
        float2 f1 = __half22float2(a0[t + 16]);
        float2 f2 = __half22float2(a0[t + 32]);
        a0x += f0.x * w0; a0y += f0.y * w0;
        a1x += f1.x * w0; a1y += f1.y * w0;
        a2x += f2.x * w0; a2y += f2.y * w0;
    }
    const float2* b2p = (const float2*)bias;
    float2 b0 = b2p[t], b1 = b2p[t + 16], b2 = b2p[t + 32];
    float h0x = fmaxf(a0x + b0.x, 0.f), h0y = fmaxf(a0y + b0.y, 0.f);
    float h1x = fmaxf(a1x + b1.x, 0.f), h1y = fmaxf(a1y + b1.y, 0.f);
    float h2x = fmaxf(a2x + b2.x, 0.f), h2y = fmaxf(a2y + b2.y, 0.f);
    __half2* o2 = (__half2*)(outh + (size_t)d * HID);
    o2[t]      = __floats2half2_rn(h0x, h0y);
    o2[t + 16] = __floats2half2_rn(h1x, h1y);
    o2[t + 32] = __floats2half2_rn(h2x, h2y);

    const int woff = (PHASE == 1) ? 0 : 96;
    const float2* wn2 = (const float2*)(Wn + woff);
    float2 w0v = wn2[t], w1v = wn2[t + 16], w2v = wn2[t + 32];
    float partial = h0x * w0v.x + h0y * w0v.y + h1x * w1v.x + h1y * w1v.y +
                    h2x * w2v.x + h2y * w2v.y;
#pragma unroll
    for (int m = 8; m; m >>= 1) partial += __shfl_down(partial, m, 16);
    if (t == 0) {
        if (PHASE == 1) nodeOut[d] = partial + bn[0];
        else            nodeOut[d] += partial;
    }
}

// ---------------- graph pooling + graph head (fp16 H inputs) ----------------
__global__ __launch_bounds__(768) void k_pool(const __half* __restrict__ h1,
                                              const __half* __restrict__ h2,
                                              const int* __restrict__ batch,
                                              const float* __restrict__ Wg,
                                              const float* __restrict__ bg,
                                              float* __restrict__ out) {
    int g = blockIdx.x;
    int tid = threadIdx.x;       // 0..767
    int way = tid / 192;         // 0..3
    int f = tid - way * 192;     // 0..191

    int lo = 0, hi = NN;
    while (lo < hi) { int mid = (lo + hi) >> 1; if (batch[mid] < g) lo = mid + 1; else hi = mid; }
    int start = lo;
    hi = NN;
    while (lo < hi) { int mid = (lo + hi) >> 1; if (batch[mid] < g + 1) lo = mid + 1; else hi = mid; }
    int end = lo;

    const __half* hsrc = (f < HID) ? h1 : h2;
    int ff = (f < HID) ? f : f - HID;
    float sum = 0.f, mx = 0.f;  // h >= 0 post-relu
    for (int n = start + way; n < end; n += 4) {
        float v = __half2float(hsrc[(size_t)n * HID + ff]);
        sum += v;
        mx = fmaxf(mx, v);
    }
    __shared__ float rsum[4][192];
    __shared__ float rmax[4][192];
    rsum[way][f] = sum;
    rmax[way][f] = mx;
    __syncthreads();
    if (way == 0) {
        sum = rsum[0][f] + rsum[1][f] + rsum[2][f] + rsum[3][f];
        mx = fmaxf(fmaxf(rmax[0][f], rmax[1][f]), fmaxf(rmax[2][f], rmax[3][f]));
        float cnt = (float)(end - start);
        float mean = sum / fmaxf(cnt, 1.0f);
        rsum[0][f] = mean * Wg[f] + mx * Wg[192 + f];
    }
    __syncthreads();
    if (tid < 64) {
        float acc = rsum[0][tid] + rsum[0][tid + 64] + rsum[0][tid + 128];
#pragma unroll
        for (int m = 32; m; m >>= 1) acc += __shfl_down(acc, m, 64);
        if (tid == 0) out[g] = acc + bg[0];
    }
}

extern "C" void kernel_launch(void* const* d_in, const int* in_sizes, int n_in,
                              void* d_out, int out_size, void* d_ws, size_t ws_size,
                              hipStream_t stream) {
    const float* x    = (const float*)d_in[0];
    const int*   ei   = (const int*)d_in[1];
    const int*   srcp = ei;
    const int*   dstp = ei + NE;
    const int*   batch = (const int*)d_in[2];
    const float* W1 = (const float*)d_in[3];
    const float* b1 = (const float*)d_in[4];
    const float* W2 = (const float*)d_in[5];
    const float* b2 = (const float*)d_in[6];
    const float* Wn = (const float*)d_in[7];
    const float* bn = (const float*)d_in[8];
    const float* Wg = (const float*)d_in[9];
    const float* bg = (const float*)d_in[10];
    float* out = (float*)d_out;

    char* p = (char*)d_ws;
    auto alloc = [&](size_t bytes) {
        char* r = p;
        p += (bytes + 255) & ~(size_t)255;
        return (void*)r;
    };
    float*    dis    = (float*)alloc(NN * 4);
    int*      off    = (int*)alloc((NN + 1) * 4);
    int*      boff   = (int*)alloc((NBK + 1) * 4);
    int*      histAB = (int*)alloc((size_t)A_BLOCKS * NBK * 4);
    unsigned* tmp    = (unsigned*)alloc((size_t)NE * 4);
    int2*     ssrcw  = (int2*)alloc((size_t)NE * 8);
    __half*   Ah     = (__half*)alloc((size_t)NN * HID * 2);   // hw buffer (both convs)
    __half*   H1h    = (__half*)alloc((size_t)NN * HID * 2);
    __half*   H2h    = (__half*)alloc((size_t)NN * HID * 2);
    __half*   W1frag = (__half*)alloc(12288 * 2);
    __half*   W2frag = (__half*)alloc(9216 * 2);

    const int TPB = 256;

    // CSR build + weight pack: [A1 ∥ pack] ; scanS ; [A3 ∥ gemm1-MFMA] ; B1 ; B2
    k_pack_a1<<<A_BLOCKS + 11, TPB, 0, stream>>>(dstp, histAB, W1, W2, W1frag, W2frag);
    k_scanS<<<1, 256, 0, stream>>>(histAB, boff);
    k_gemm1_a3<<<A_BLOCKS + GEMM1_BLOCKS, 256, 0, stream>>>(
        x, W1frag, Ah, srcp, dstp, boff, histAB, tmp);
    k_B1<<<NBK, 256, 0, stream>>>(tmp, boff, off, dis);
    k_B2<<<NBK, 256, 0, stream>>>(tmp, boff, off, dis, ssrcw);

    const int aggThreads = NN * 16;
    float* nodeOut = out + NG;

    // conv1 aggregate (16-lane half2): H1h ; nodeOut partial 1
    k_agg<1><<<(aggThreads + TPB - 1) / TPB, TPB, 0, stream>>>(Ah, ssrcw, off, dis, b1, Wn, bn, H1h, nodeOut);

    // conv2 transform (MFMA, standalone)
    k_gemm2<<<G2_BLOCKS, 256, 0, stream>>>(H1h, W2frag, Ah);

    // conv2 aggregate: H2h ; nodeOut partial 2
    k_agg<2><<<(aggThreads + TPB - 1) / TPB, TPB, 0, stream>>>(Ah, ssrcw, off, dis, b2, Wn, bn, H2h, nodeOut);

    // pooling + graph head
    k_pool<<<NG, 768, 0, stream>>>(H1h, H2h, batch, Wg, bg, out);
}

// Round 17
// 244.034 us; speedup vs baseline: 1.3663x; 1.0169x over previous
//
#include <hip/hip_runtime.h>
#include <hip/hip_fp16.h>

#define NN 100000      // nodes
#define NE 1600000     // edges
#define INC 128        // in channels
#define HID 96         // hidden
#define NG 512         // graphs

#define GEMM1_BLOCKS 1563        // ceil(NN/64)
#define G2_BLOCKS 1563           // ceil(NN/64) for MFMA gemm2

#define BK_SHIFT 9
#define BK_SIZE 512
#define NBK 196                  // ceil(NN/512)
#define A_EPB 4096               // edges per A-pass block
#define A_BLOCKS 391             // ceil(NE/4096)

typedef _Float16 half8 __attribute__((ext_vector_type(8)));
typedef float f32x4 __attribute__((ext_vector_type(4)));

// ---------------- FUSED: A1 (per-block bucket histogram) ∥ W1+W2 frag pack ----------------
__global__ __launch_bounds__(256) void k_pack_a1(const int* __restrict__ dst,
                                                 int* __restrict__ histAB,
                                                 const float* __restrict__ W1,
                                                 const float* __restrict__ W2,
                                                 __half* __restrict__ W1frag,
                                                 __half* __restrict__ W2frag) {
    const int tid = threadIdx.x;
    if (blockIdx.x < A_BLOCKS) {
        __shared__ int cnt[NBK];
        int ab = blockIdx.x;
        for (int i = tid; i < NBK; i += 256) cnt[i] = 0;
        __syncthreads();
        int e0 = ab * A_EPB;
#pragma unroll 4
        for (int q = 0; q < A_EPB / 256; ++q) {
            int e = e0 + q * 256 + tid;
            if (e < NE) atomicAdd(&cnt[dst[e] >> BK_SHIFT], 1);
        }
        __syncthreads();
        for (int i = tid; i < NBK; i += 256) histAB[ab * NBK + i] = cnt[i];
        return;
    }
    int p = (blockIdx.x - A_BLOCKS) * 256 + tid;
    if (p < 1536) {
        int kc = p / 384;
        int rem = p - kc * 384;
        int ct = rem >> 6;
        int l = rem & 63;
#pragma unroll
        for (int i = 0; i < 8; ++i) {
            int k = kc * 32 + ((l >> 4) << 3) + i;
            int c = ct * 16 + (l & 15);
            W1frag[p * 8 + i] = __float2half(W1[k * HID + c]);
        }
    } else {
        int q = p - 1536;
        if (q >= 1152) return;
        int kc = q / 384;
        int rem = q - kc * 384;
        int ct = rem >> 6;
        int l = rem & 63;
#pragma unroll
        for (int i = 0; i < 8; ++i) {
            int k = kc * 32 + ((l >> 4) << 3) + i;
            int c = ct * 16 + (l & 15);
            W2frag[q * 8 + i] = __float2half(W2[k * HID + c]);
        }
    }
}

// ---------------- scanS: column prefix of histAB + bucket prefix -> boff ----------------
__global__ __launch_bounds__(256) void k_scanS(int* __restrict__ histAB, int* __restrict__ boff) {
    __shared__ int tot[256];
    int t = threadIdx.x;
    int run = 0;
    if (t < NBK) {
        for (int blk = 0; blk < A_BLOCKS; ++blk) {
            int idx = blk * NBK + t;
            int v = histAB[idx];
            histAB[idx] = run;
            run += v;
        }
    }
    tot[t] = (t < NBK) ? run : 0;
    __syncthreads();
    for (int ofs = 1; ofs < 256; ofs <<= 1) {
        int v = (t >= ofs) ? tot[t - ofs] : 0;
        __syncthreads();
        tot[t] += v;
        __syncthreads();
    }
    if (t == 0) boff[0] = 0;
    if (t < NBK) boff[t + 1] = tot[t];
}

// ---------------- FUSED: A3 (binned edge write) ∥ gemm1 (MFMA fp16) ----------------
__global__ __launch_bounds__(256) void k_gemm1_a3(
        const float* __restrict__ X, const __half* __restrict__ W1frag,
        __half* __restrict__ Yh,
        const int* __restrict__ src, const int* __restrict__ dst,
        const int* __restrict__ boff, const int* __restrict__ histAB,
        unsigned* __restrict__ tmp) {
    __shared__ __half w1s[12288];
    const int tid = threadIdx.x;

    if (blockIdx.x < A_BLOCKS) {
        int* base = (int*)w1s;
        int* lcnt = base + NBK;
        int ab = blockIdx.x;
        for (int i = tid; i < NBK; i += 256) {
            base[i] = boff[i] + histAB[ab * NBK + i];
            lcnt[i] = 0;
        }
        __syncthreads();
        int e0 = ab * A_EPB;
#pragma unroll 4
        for (int q = 0; q < A_EPB / 256; ++q) {
            int e = e0 + q * 256 + tid;
            if (e < NE) {
                int d = dst[e];
                int bk = d >> BK_SHIFT;
                int lp = atomicAdd(&lcnt[bk], 1);
                tmp[base[bk] + lp] = (unsigned)src[e] | ((unsigned)(d & (BK_SIZE - 1)) << 17);
            }
        }
        return;
    }

    // ---- gemm1 MFMA body (K = 128, 4 steps) ----
    {
        half8* d8 = (half8*)w1s;
        const half8* s8 = (const half8*)W1frag;
        for (int i = tid; i < 1536; i += 256) d8[i] = s8[i];
    }
    __syncthreads();
    const int w = tid >> 6;
    const int l = tid & 63;
    const int row0 = (blockIdx.x - A_BLOCKS) * 64 + w * 16;
    int arow = row0 + (l & 15);
    if (arow >= NN) arow = NN - 1;
    f32x4 acc[6] = {};
#pragma unroll
    for (int kc = 0; kc < 4; ++kc) {
        const float* xp = &X[(size_t)arow * INC + kc * 32 + ((l >> 4) << 3)];
        float4 xa = *(const float4*)xp;
        float4 xb = *(const float4*)(xp + 4);
        half8 a;
        a[0] = (_Float16)xa.x; a[1] = (_Float16)xa.y;
        a[2] = (_Float16)xa.z; a[3] = (_Float16)xa.w;
        a[4] = (_Float16)xb.x; a[5] = (_Float16)xb.y;
        a[6] = (_Float16)xb.z; a[7] = (_Float16)xb.w;
#pragma unroll
        for (int ct = 0; ct < 6; ++ct) {
            half8 b = *(const half8*)&w1s[((kc * 6 + ct) * 64 + l) * 8];
            acc[ct] = __builtin_amdgcn_mfma_f32_16x16x32_f16(a, b, acc[ct], 0, 0, 0);
        }
    }
    const int orow = row0 + ((l >> 4) << 2);
    const int col = l & 15;
#pragma unroll
    for (int ct = 0; ct < 6; ++ct)
#pragma unroll
        for (int i = 0; i < 4; ++i) {
            int r = orow + i;
            if (r < NN) Yh[(size_t)r * HID + ct * 16 + col] = __float2half(acc[ct][i]);
        }
}

// ---------------- B1: per-bucket degree count -> off (+dis), zero global atomics ----------
__global__ __launch_bounds__(256) void k_B1(const unsigned* __restrict__ tmp,
                                            const int* __restrict__ boff,
                                            int* __restrict__ off, float* __restrict__ dis) {
    __shared__ int cnt[BK_SIZE];
    __shared__ int psum[256];
    const int t = threadIdx.x;
    const int b = blockIdx.x;
    const int nb = b << BK_SHIFT;
    const int rbeg = boff[b], rend = boff[b + 1];
    cnt[t] = 0; cnt[t + 256] = 0;
    __syncthreads();
    for (int e = rbeg + t; e < rend; e += 256) {
        unsigned u = tmp[e];
        atomicAdd(&cnt[u >> 17], 1);
    }
    __syncthreads();
    int c0 = cnt[2 * t], c1 = cnt[2 * t + 1];
    int pairSum = c0 + c1;
    psum[t] = pairSum;
    __syncthreads();
    for (int ofs = 1; ofs < 256; ofs <<= 1) {
        int v = (t >= ofs) ? psum[t - ofs] : 0;
        __syncthreads();
        psum[t] += v;
        __syncthreads();
    }
    int pairExcl = psum[t] - pairSum;
    int node0 = nb + 2 * t, node1 = node0 + 1;
    if (node0 < NN) {
        off[node0] = rbeg + pairExcl;
        dis[node0] = rsqrtf((float)(c0 + 1));
    }
    if (node1 < NN) {
        off[node1] = rbeg + pairExcl + c0;
        dis[node1] = rsqrtf((float)(c1 + 1));
    }
    if (b == NBK - 1 && t == 0) off[NN] = rend;
}

// ---------------- B2: per-bucket scatter into final CSR {src, w} ----------------
__global__ __launch_bounds__(256) void k_B2(const unsigned* __restrict__ tmp,
                                            const int* __restrict__ boff,
                                            const int* __restrict__ off,
                                            const float* __restrict__ dis,
                                            int2* __restrict__ ssrcw) {
    __shared__ int cnt[BK_SIZE];
    const int tid = threadIdx.x;
    const int b = blockIdx.x;
    const int nb = b << BK_SHIFT;
    const int rbeg = boff[b], rend = boff[b + 1];
    cnt[tid] = 0; cnt[tid + 256] = 0;
    __syncthreads();
    for (int e = rbeg + tid; e < rend; e += 256) {
        unsigned u = tmp[e];
        int s = (int)(u & 0x1FFFFu);
        int dl = (int)(u >> 17);
        int d = nb + dl;
        int pos = off[d] + atomicAdd(&cnt[dl], 1);
        float w = dis[s] * dis[d];
        ssrcw[pos] = make_int2(s, __float_as_int(w));
    }
}

// ---------------- GEMM2 (MFMA fp16, standalone; layout HW-validated round 10) ----------------
__global__ __launch_bounds__(256) void k_gemm2(const __half* __restrict__ Xh,
                                               const __half* __restrict__ W2frag,
                                               __half* __restrict__ Yh) {
    __shared__ __half w2s[9216];
    const int tid = threadIdx.x;
    {
        half8* d8 = (half8*)w2s;
        const half8* s8 = (const half8*)W2frag;
        for (int i = tid; i < 1152; i += 256) d8[i] = s8[i];
    }
    __syncthreads();
    const int w = tid >> 6;
    const int l = tid & 63;
    const int row0 = blockIdx.x * 64 + w * 16;
    int arow = row0 + (l & 15);
    if (arow >= NN) arow = NN - 1;
    f32x4 acc[6] = {};
#pragma unroll
    for (int kc = 0; kc < 3; ++kc) {
        half8 a = *(const half8*)&Xh[(size_t)arow * HID + kc * 32 + ((l >> 4) << 3)];
#pragma unroll
        for (int ct = 0; ct < 6; ++ct) {
            half8 b = *(const half8*)&w2s[((kc * 6 + ct) * 64 + l) * 8];
            acc[ct] = __builtin_amdgcn_mfma_f32_16x16x32_f16(a, b, acc[ct], 0, 0, 0);
        }
    }
    const int orow = row0 + ((l >> 4) << 2);
    const int col = l & 15;
#pragma unroll
    for (int ct = 0; ct < 6; ++ct)
#pragma unroll
        for (int i = 0; i < 4; ++i) {
            int r = orow + i;
            if (r < NN) Yh[(size_t)r * HID + ct * 16 + col] = __float2half(acc[ct][i]);
        }
}

// ---------------- agg batch helper: B edges, NT descriptor loads ----------------
template <int B>
__device__ __forceinline__ void agg_batch(const __half* __restrict__ Ah,
                                          const int2* __restrict__ ssrcw, int j, int t,
                                          float& a0x, float& a0y, float& a1x, float& a1y,
                                          float& a2x, float& a2y) {
    long ed[B];
#pragma unroll
    for (int q = 0; q < B; ++q)
        ed[q] = __builtin_nontemporal_load((const long*)&ssrcw[j + q]);
    float w[B];
    const __half2* ap[B];
#pragma unroll
    for (int q = 0; q < B; ++q) {
        int s = (int)(unsigned)(ed[q] & 0xFFFFFFFFL);
        w[q] = __int_as_float((int)(ed[q] >> 32));
        ap[q] = (const __half2*)(Ah + (size_t)s * HID);
    }
    __half2 g0[B], g1[B], g2[B];
#pragma unroll
    for (int q = 0; q < B; ++q) {
        g0[q] = ap[q][t];
        g1[q] = ap[q][t + 16];
        g2[q] = ap[q][t + 32];
    }
#pragma unroll
    for (int q = 0; q < B; ++q) {
        float2 f0 = __half22float2(g0[q]);
        float2 f1 = __half22float2(g1[q]);
        float2 f2 = __half22float2(g2[q]);
        a0x += f0.x * w[q]; a0y += f0.y * w[q];
        a1x += f1.x * w[q]; a1y += f1.y * w[q];
        a2x += f2.x * w[q]; a2y += f2.y * w[q];
    }
}

// ---------------- fused GCN aggregation + node-logit partial (16 lanes/dst, half2) ------
template <int PHASE>
__global__ __launch_bounds__(256) void k_agg(const __half* __restrict__ Ah,
                                             const int2* __restrict__ ssrcw,
                                             const int* __restrict__ off,
                                             const float* __restrict__ dis,
                                             const float* __restrict__ bias,
                                             const float* __restrict__ Wn,
                                             const float* __restrict__ bn,
                                             __half* __restrict__ outh,
                                             float* __restrict__ nodeOut) {
    int gid = blockIdx.x * blockDim.x + threadIdx.x;
    int d = gid >> 4;
    int t = gid & 15;
    if (d >= NN) return;
    const int beg = off[d], end = off[d + 1];
    const float dd = dis[d];
    const __half2* ad2 = (const __half2*)(Ah + (size_t)d * HID);
    float2 s0 = __half22float2(ad2[t]);
    float2 s1 = __half22float2(ad2[t + 16]);
    float2 s2 = __half22float2(ad2[t + 32]);
    const float dd2 = dd * dd;
    float a0x = s0.x * dd2, a0y = s0.y * dd2;
    float a1x = s1.x * dd2, a1y = s1.y * dd2;
    float a2x = s2.x * dd2, a2y = s2.y * dd2;
    int j = beg;
    for (; j + 11 < end; j += 12)
        agg_batch<12>(Ah, ssrcw, j, t, a0x, a0y, a1x, a1y, a2x, a2y);
    for (; j + 3 < end; j += 4)
        agg_batch<4>(Ah, ssrcw, j, t, a0x, a0y, a1x, a1y, a2x, a2y);
    for (; j < end; ++j) {
        int2 e0 = ssrcw[j];
        float w0 = __int_as_float(e0.y);
        const __half2* a0 = (const __half2*)(Ah + (size_t)e0.x * HID);
        float2 f0 = __half22float2(a0[t]);
        float2 f1 = __half22float2(a0[t + 16]);
        float2 f2 = __half22float2(a0[t + 32]);
        a0x += f0.x * w0; a0y += f0.y * w0;
        a1x += f1.x * w0; a1y += f1.y * w0;
        a2x += f2.x * w0; a2y += f2.y * w0;
    }
    const float2* b2p = (const float2*)bias;
    float2 b0 = b2p[t], b1 = b2p[t + 16], b2 = b2p[t + 32];
    float h0x = fmaxf(a0x + b0.x, 0.f), h0y = fmaxf(a0y + b0.y, 0.f);
    float h1x = fmaxf(a1x + b1.x, 0.f), h1y = fmaxf(a1y + b1.y, 0.f);
    float h2x = fmaxf(a2x + b2.x, 0.f), h2y = fmaxf(a2y + b2.y, 0.f);
    __half2* o2 = (__half2*)(outh + (size_t)d * HID);
    o2[t]      = __floats2half2_rn(h0x, h0y);
    o2[t + 16] = __floats2half2_rn(h1x, h1y);
    o2[t + 32] = __floats2half2_rn(h2x, h2y);

    const int woff = (PHASE == 1) ? 0 : 96;
    const float2* wn2 = (const float2*)(Wn + woff);
    float2 w0v = wn2[t], w1v = wn2[t + 16], w2v = wn2[t + 32];
    float partial = h0x * w0v.x + h0y * w0v.y + h1x * w1v.x + h1y * w1v.y +
                    h2x * w2v.x + h2y * w2v.y;
#pragma unroll
    for (int m = 8; m; m >>= 1) partial += __shfl_down(partial, m, 16);
    if (t == 0) {
        if (PHASE == 1) nodeOut[d] = partial + bn[0];
        else            nodeOut[d] += partial;
    }
}

// ---------------- graph pooling + graph head (fp16 H inputs, 2x node unroll) ----------------
__global__ __launch_bounds__(768) void k_pool(const __half* __restrict__ h1,
                                              const __half* __restrict__ h2,
                                              const int* __restrict__ batch,
                                              const float* __restrict__ Wg,
                                              const float* __restrict__ bg,
                                              float* __restrict__ out) {
    int g = blockIdx.x;
    int tid = threadIdx.x;       // 0..767
    int way = tid / 192;         // 0..3
    int f = tid - way * 192;     // 0..191

    int lo = 0, hi = NN;
    while (lo < hi) { int mid = (lo + hi) >> 1; if (batch[mid] < g) lo = mid + 1; else hi = mid; }
    int start = lo;
    hi = NN;
    while (lo < hi) { int mid = (lo + hi) >> 1; if (batch[mid] < g + 1) lo = mid + 1; else hi = mid; }
    int end = lo;

    const __half* hsrc = (f < HID) ? h1 : h2;
    int ff = (f < HID) ? f : f - HID;
    float sum = 0.f, mx = 0.f;  // h >= 0 post-relu
    int n = start + way;
    for (; n + 4 < end; n += 8) {
        float v0 = __half2float(hsrc[(size_t)n * HID + ff]);
        float v1 = __half2float(hsrc[(size_t)(n + 4) * HID + ff]);
        sum += v0 + v1;
        mx = fmaxf(mx, fmaxf(v0, v1));
    }
    if (n < end) {
        float v0 = __half2float(hsrc[(size_t)n * HID + ff]);
        sum += v0;
        mx = fmaxf(mx, v0);
    }
    __shared__ float rsum[4][192];
    __shared__ float rmax[4][192];
    rsum[way][f] = sum;
    rmax[way][f] = mx;
    __syncthreads();
    if (way == 0) {
        sum = rsum[0][f] + rsum[1][f] + rsum[2][f] + rsum[3][f];
        mx = fmaxf(fmaxf(rmax[0][f], rmax[1][f]), fmaxf(rmax[2][f], rmax[3][f]));
        float cnt = (float)(end - start);
        float mean = sum / fmaxf(cnt, 1.0f);
        rsum[0][f] = mean * Wg[f] + mx * Wg[192 + f];
    }
    __syncthreads();
    if (tid < 64) {
        float acc = rsum[0][tid] + rsum[0][tid + 64] + rsum[0][tid + 128];
#pragma unroll
        for (int m = 32; m; m >>= 1) acc += __shfl_down(acc, m, 64);
        if (tid == 0) out[g] = acc + bg[0];
    }
}

extern "C" void kernel_launch(void* const* d_in, const int* in_sizes, int n_in,
                              void* d_out, int out_size, void* d_ws, size_t ws_size,
                              hipStream_t stream) {
    const float* x    = (const float*)d_in[0];
    const int*   ei   = (const int*)d_in[1];
    const int*   srcp = ei;
    const int*   dstp = ei + NE;
    const int*   batch = (const int*)d_in[2];
    const float* W1 = (const float*)d_in[3];
    const float* b1 = (const float*)d_in[4];
    const float* W2 = (const float*)d_in[5];
    const float* b2 = (const float*)d_in[6];
    const float* Wn = (const float*)d_in[7];
    const float* bn = (const float*)d_in[8];
    const float* Wg = (const float*)d_in[9];
    const float* bg = (const float*)d_in[10];
    float* out = (float*)d_out;

    char* p = (char*)d_ws;
    auto alloc = [&](size_t bytes) {
        char* r = p;
        p += (bytes + 255) & ~(size_t)255;
        return (void*)r;
    };
    float*    dis    = (float*)alloc(NN * 4);
    int*      off    = (int*)alloc((NN + 1) * 4);
    int*      boff   = (int*)alloc((NBK + 1) * 4);
    int*      histAB = (int*)alloc((size_t)A_BLOCKS * NBK * 4);
    unsigned* tmp    = (unsigned*)alloc((size_t)NE * 4);
    int2*     ssrcw  = (int2*)alloc((size_t)NE * 8);
    __half*   Ah     = (__half*)alloc((size_t)NN * HID * 2);   // hw buffer (both convs)
    __half*   H1h    = (__half*)alloc((size_t)NN * HID * 2);
    __half*   H2h    = (__half*)alloc((size_t)NN * HID * 2);
    __half*   W1frag = (__half*)alloc(12288 * 2);
    __half*   W2frag = (__half*)alloc(9216 * 2);

    const int TPB = 256;

    // CSR build + weight pack: [A1 ∥ pack] ; scanS ; [A3 ∥ gemm1-MFMA] ; B1 ; B2
    k_pack_a1<<<A_BLOCKS + 11, TPB, 0, stream>>>(dstp, histAB, W1, W2, W1frag, W2frag);
    k_scanS<<<1, 256, 0, stream>>>(histAB, boff);
    k_gemm1_a3<<<A_BLOCKS + GEMM1_BLOCKS, 256, 0, stream>>>(
        x, W1frag, Ah, srcp, dstp, boff, histAB, tmp);
    k_B1<<<NBK, 256, 0, stream>>>(tmp, boff, off, dis);
    k_B2<<<NBK, 256, 0, stream>>>(tmp, boff, off, dis, ssrcw);

    const int aggThreads = NN * 16;
    float* nodeOut = out + NG;

    // conv1 aggregate (16-lane half2): H1h ; nodeOut partial 1
    k_agg<1><<<(aggThreads + TPB - 1) / TPB, TPB, 0, stream>>>(Ah, ssrcw, off, dis, b1, Wn, bn, H1h, nodeOut);

    // conv2 transform (MFMA, standalone)
    k_gemm2<<<G2_BLOCKS, 256, 0, stream>>>(H1h, W2frag, Ah);

    // conv2 aggregate: H2h ; nodeOut partial 2
    k_agg<2><<<(aggThreads + TPB - 1) / TPB, TPB, 0, stream>>>(Ah, ssrcw, off, dis, b2, Wn, bn, H2h, nodeOut);

    // pooling + graph head
    k_pool<<<NG, 768, 0, stream>>>(H1h, H2h, batch, Wg, bg, out);
}

// Round 18
// 241.761 us; speedup vs baseline: 1.3791x; 1.0094x over previous
//
#include <hip/hip_runtime.h>
#include <hip/hip_fp16.h>

#define NN 100000      // nodes
#define NE 1600000     // edges
#define INC 128        // in channels
#define HID 96         // hidden
#define NG 512         // graphs

#define GEMM1_BLOCKS 1563        // ceil(NN/64)
#define G2_BLOCKS 1563           // ceil(NN/64) for MFMA gemm2

#define BK_SHIFT 9
#define BK_SIZE 512
#define NBK 196                  // ceil(NN/512)
#define A_EPB 4096               // edges per A-pass block
#define A_BLOCKS 391             // ceil(NE/4096)

typedef _Float16 half8 __attribute__((ext_vector_type(8)));
typedef float f32x4 __attribute__((ext_vector_type(4)));

// ---------------- FUSED: A1 (per-block bucket histogram) ∥ W1+W2 frag pack ----------------
__global__ __launch_bounds__(256) void k_pack_a1(const int* __restrict__ dst,
                                                 int* __restrict__ histAB,
                                                 const float* __restrict__ W1,
                                                 const float* __restrict__ W2,
                                                 __half* __restrict__ W1frag,
                                                 __half* __restrict__ W2frag) {
    const int tid = threadIdx.x;
    if (blockIdx.x < A_BLOCKS) {
        __shared__ int cnt[NBK];
        int ab = blockIdx.x;
        for (int i = tid; i < NBK; i += 256) cnt[i] = 0;
        __syncthreads();
        int e0 = ab * A_EPB;
#pragma unroll 4
        for (int q = 0; q < A_EPB / 256; ++q) {
            int e = e0 + q * 256 + tid;
            if (e < NE) atomicAdd(&cnt[dst[e] >> BK_SHIFT], 1);
        }
        __syncthreads();
        for (int i = tid; i < NBK; i += 256) histAB[ab * NBK + i] = cnt[i];
        return;
    }
    int p = (blockIdx.x - A_BLOCKS) * 256 + tid;
    if (p < 1536) {
        int kc = p / 384;
        int rem = p - kc * 384;
        int ct = rem >> 6;
        int l = rem & 63;
#pragma unroll
        for (int i = 0; i < 8; ++i) {
            int k = kc * 32 + ((l >> 4) << 3) + i;
            int c = ct * 16 + (l & 15);
            W1frag[p * 8 + i] = __float2half(W1[k * HID + c]);
        }
    } else {
        int q = p - 1536;
        if (q >= 1152) return;
        int kc = q / 384;
        int rem = q - kc * 384;
        int ct = rem >> 6;
        int l = rem & 63;
#pragma unroll
        for (int i = 0; i < 8; ++i) {
            int k = kc * 32 + ((l >> 4) << 3) + i;
            int c = ct * 16 + (l & 15);
            W2frag[q * 8 + i] = __float2half(W2[k * HID + c]);
        }
    }
}

// ---------------- scanS: column prefix of histAB + bucket prefix -> boff ----------------
__global__ __launch_bounds__(256) void k_scanS(int* __restrict__ histAB, int* __restrict__ boff) {
    __shared__ int tot[256];
    int t = threadIdx.x;
    int run = 0;
    if (t < NBK) {
        for (int blk = 0; blk < A_BLOCKS; ++blk) {
            int idx = blk * NBK + t;
            int v = histAB[idx];
            histAB[idx] = run;
            run += v;
        }
    }
    tot[t] = (t < NBK) ? run : 0;
    __syncthreads();
    for (int ofs = 1; ofs < 256; ofs <<= 1) {
        int v = (t >= ofs) ? tot[t - ofs] : 0;
        __syncthreads();
        tot[t] += v;
        __syncthreads();
    }
    if (t == 0) boff[0] = 0;
    if (t < NBK) boff[t + 1] = tot[t];
}

// ---------------- FUSED: A3 (binned edge write) ∥ gemm1 (MFMA fp16) ----------------
__global__ __launch_bounds__(256) void k_gemm1_a3(
        const float* __restrict__ X, const __half* __restrict__ W1frag,
        __half* __restrict__ Yh,
        const int* __restrict__ src, const int* __restrict__ dst,
        const int* __restrict__ boff, const int* __restrict__ histAB,
        unsigned* __restrict__ tmp) {
    __shared__ __half w1s[12288];
    const int tid = threadIdx.x;

    if (blockIdx.x < A_BLOCKS) {
        int* base = (int*)w1s;
        int* lcnt = base + NBK;
        int ab = blockIdx.x;
        for (int i = tid; i < NBK; i += 256) {
            base[i] = boff[i] + histAB[ab * NBK + i];
            lcnt[i] = 0;
        }
        __syncthreads();
        int e0 = ab * A_EPB;
#pragma unroll 4
        for (int q = 0; q < A_EPB / 256; ++q) {
            int e = e0 + q * 256 + tid;
            if (e < NE) {
                int d = dst[e];
                int bk = d >> BK_SHIFT;
                int lp = atomicAdd(&lcnt[bk], 1);
                tmp[base[bk] + lp] = (unsigned)src[e] | ((unsigned)(d & (BK_SIZE - 1)) << 17);
            }
        }
        return;
    }

    // ---- gemm1 MFMA body (K = 128, 4 steps) ----
    {
        half8* d8 = (half8*)w1s;
        const half8* s8 = (const half8*)W1frag;
        for (int i = tid; i < 1536; i += 256) d8[i] = s8[i];
    }
    __syncthreads();
    const int w = tid >> 6;
    const int l = tid & 63;
    const int row0 = (blockIdx.x - A_BLOCKS) * 64 + w * 16;
    int arow = row0 + (l & 15);
    if (arow >= NN) arow = NN - 1;
    f32x4 acc[6] = {};
#pragma unroll
    for (int kc = 0; kc < 4; ++kc) {
        const float* xp = &X[(size_t)arow * INC + kc * 32 + ((l >> 4) << 3)];
        float4 xa = *(const float4*)xp;
        float4 xb = *(const float4*)(xp + 4);
        half8 a;
        a[0] = (_Float16)xa.x; a[1] = (_Float16)xa.y;
        a[2] = (_Float16)xa.z; a[3] = (_Float16)xa.w;
        a[4] = (_Float16)xb.x; a[5] = (_Float16)xb.y;
        a[6] = (_Float16)xb.z; a[7] = (_Float16)xb.w;
#pragma unroll
        for (int ct = 0; ct < 6; ++ct) {
            half8 b = *(const half8*)&w1s[((kc * 6 + ct) * 64 + l) * 8];
            acc[ct] = __builtin_amdgcn_mfma_f32_16x16x32_f16(a, b, acc[ct], 0, 0, 0);
        }
    }
    const int orow = row0 + ((l >> 4) << 2);
    const int col = l & 15;
#pragma unroll
    for (int ct = 0; ct < 6; ++ct)
#pragma unroll
        for (int i = 0; i < 4; ++i) {
            int r = orow + i;
            if (r < NN) Yh[(size_t)r * HID + ct * 16 + col] = __float2half(acc[ct][i]);
        }
}

// ---------------- FUSED B: count -> prefix -> off/dis -> scatter 4B src ----------------
__global__ __launch_bounds__(256) void k_B(const unsigned* __restrict__ tmp,
                                           const int* __restrict__ boff,
                                           int* __restrict__ off, float* __restrict__ dis,
                                           int* __restrict__ ssrc) {
    __shared__ int cnt[BK_SIZE];
    __shared__ int psum[256];
    __shared__ int cur[BK_SIZE];
    const int t = threadIdx.x;
    const int b = blockIdx.x;
    const int nb = b << BK_SHIFT;
    const int rbeg = boff[b], rend = boff[b + 1];
    cnt[t] = 0; cnt[t + 256] = 0;
    __syncthreads();
    for (int e = rbeg + t; e < rend; e += 256) {
        unsigned u = tmp[e];
        atomicAdd(&cnt[u >> 17], 1);
    }
    __syncthreads();
    int c0 = cnt[2 * t], c1 = cnt[2 * t + 1];
    int pairSum = c0 + c1;
    psum[t] = pairSum;
    __syncthreads();
    for (int ofs = 1; ofs < 256; ofs <<= 1) {
        int v = (t >= ofs) ? psum[t - ofs] : 0;
        __syncthreads();
        psum[t] += v;
        __syncthreads();
    }
    int pairExcl = psum[t] - pairSum;
    cur[2 * t] = pairExcl;
    cur[2 * t + 1] = pairExcl + c0;
    int node0 = nb + 2 * t, node1 = node0 + 1;
    if (node0 < NN) {
        off[node0] = rbeg + pairExcl;
        dis[node0] = rsqrtf((float)(c0 + 1));
    }
    if (node1 < NN) {
        off[node1] = rbeg + pairExcl + c0;
        dis[node1] = rsqrtf((float)(c1 + 1));
    }
    if (b == NBK - 1 && t == 0) off[NN] = rend;
    __syncthreads();
    // scatter pass (tmp L2-hot from pass 1)
    for (int e = rbeg + t; e < rend; e += 256) {
        unsigned u = tmp[e];
        int dl = (int)(u >> 17);
        int pos = rbeg + atomicAdd(&cur[dl], 1);
        ssrc[pos] = (int)(u & 0x1FFFFu);
    }
}

// ---------------- GEMM2 (MFMA fp16, standalone; layout HW-validated round 10) ----------------
__global__ __launch_bounds__(256) void k_gemm2(const __half* __restrict__ Xh,
                                               const __half* __restrict__ W2frag,
                                               __half* __restrict__ Yh) {
    __shared__ __half w2s[9216];
    const int tid = threadIdx.x;
    {
        half8* d8 = (half8*)w2s;
        const half8* s8 = (const half8*)W2frag;
        for (int i = tid; i < 1152; i += 256) d8[i] = s8[i];
    }
    __syncthreads();
    const int w = tid >> 6;
    const int l = tid & 63;
    const int row0 = blockIdx.x * 64 + w * 16;
    int arow = row0 + (l & 15);
    if (arow >= NN) arow = NN - 1;
    f32x4 acc[6] = {};
#pragma unroll
    for (int kc = 0; kc < 3; ++kc) {
        half8 a = *(const half8*)&Xh[(size_t)arow * HID + kc * 32 + ((l >> 4) << 3)];
#pragma unroll
        for (int ct = 0; ct < 6; ++ct) {
            half8 b = *(const half8*)&w2s[((kc * 6 + ct) * 64 + l) * 8];
            acc[ct] = __builtin_amdgcn_mfma_f32_16x16x32_f16(a, b, acc[ct], 0, 0, 0);
        }
    }
    const int orow = row0 + ((l >> 4) << 2);
    const int col = l & 15;
#pragma unroll
    for (int ct = 0; ct < 6; ++ct)
#pragma unroll
        for (int i = 0; i < 4; ++i) {
            int r = orow + i;
            if (r < NN) Yh[(size_t)r * HID + ct * 16 + col] = __float2half(acc[ct][i]);
        }
}

// ---------------- agg batch helper: B edges, 4B descriptors + dis gather ----------------
template <int B>
__device__ __forceinline__ void agg_batch(const __half* __restrict__ Ah,
                                          const int* __restrict__ ssrc,
                                          const float* __restrict__ dis, float dd,
                                          int j, int t,
                                          float& a0x, float& a0y, float& a1x, float& a1y,
                                          float& a2x, float& a2y) {
    int s[B];
#pragma unroll
    for (int q = 0; q < B; ++q) s[q] = ssrc[j + q];
    float w[B];
    const __half2* ap[B];
#pragma unroll
    for (int q = 0; q < B; ++q) {
        w[q] = dis[s[q]] * dd;
        ap[q] = (const __half2*)(Ah + (size_t)s[q] * HID);
    }
    __half2 g0[B], g1[B], g2[B];
#pragma unroll
    for (int q = 0; q < B; ++q) {
        g0[q] = ap[q][t];
        g1[q] = ap[q][t + 16];
        g2[q] = ap[q][t + 32];
    }
#pragma unroll
    for (int q = 0; q < B; ++q) {
        float2 f0 = __half22float2(g0[q]);
        float2 f1 = __half22float2(g1[q]);
        float2 f2 = __half22float2(g2[q]);
        a0x += f0.x * w[q]; a0y += f0.y * w[q];
        a1x += f1.x * w[q]; a1y += f1.y * w[q];
        a2x += f2.x * w[q]; a2y += f2.y * w[q];
    }
}

// ---------------- fused GCN aggregation + node-logit partial (16 lanes/dst, half2) ------
template <int PHASE>
__global__ __launch_bounds__(256) void k_agg(const __half* __restrict__ Ah,
                                             const int* __restrict__ ssrc,
                                             const int* __restrict__ off,
                                             const float* __restrict__ dis,
                                             const float* __restrict__ bias,
                                             const float* __restrict__ Wn,
                                             const float* __restrict__ bn,
                                             __half* __restrict__ outh,
                                             float* __restrict__ nodeOut) {
    int gid = blockIdx.x * blockDim.x + threadIdx.x;
    int d = gid >> 4;
    int t = gid & 15;
    if (d >= NN) return;
    const int beg = off[d], end = off[d + 1];
    const float dd = dis[d];
    const __half2* ad2 = (const __half2*)(Ah + (size_t)d * HID);
    float2 s0 = __half22float2(ad2[t]);
    float2 s1 = __half22float2(ad2[t + 16]);
    float2 s2 = __half22float2(ad2[t + 32]);
    const float dd2 = dd * dd;
    float a0x = s0.x * dd2, a0y = s0.y * dd2;
    float a1x = s1.x * dd2, a1y = s1.y * dd2;
    float a2x = s2.x * dd2, a2y = s2.y * dd2;
    int j = beg;
    for (; j + 11 < end; j += 12)
        agg_batch<12>(Ah, ssrc, dis, dd, j, t, a0x, a0y, a1x, a1y, a2x, a2y);
    for (; j + 3 < end; j += 4)
        agg_batch<4>(Ah, ssrc, dis, dd, j, t, a0x, a0y, a1x, a1y, a2x, a2y);
    for (; j < end; ++j) {
        int s = ssrc[j];
        float w0 = dis[s] * dd;
        const __half2* a0 = (const __half2*)(Ah + (size_t)s * HID);
        float2 f0 = __half22float2(a0[t]);
        float2 f1 = __half22float2(a0[t + 16]);
        float2 f2 = __half22float2(a0[t + 32]);
        a0x += f0.x * w0; a0y += f0.y * w0;
        a1x += f1.x * w0; a1y += f1.y * w0;
        a2x += f2.x * w0; a2y += f2.y * w0;
    }
    const float2* b2p = (const float2*)bias;
    float2 b0 = b2p[t], b1 = b2p[t + 16], b2 = b2p[t + 32];
    float h0x = fmaxf(a0x + b0.x, 0.f), h0y = fmaxf(a0y + b0.y, 0.f);
    float h1x = fmaxf(a1x + b1.x, 0.f), h1y = fmaxf(a1y + b1.y, 0.f);
    float h2x = fmaxf(a2x + b2.x, 0.f), h2y = fmaxf(a2y + b2.y, 0.f);
    __half2* o2 = (__half2*)(outh + (size_t)d * HID);
    o2[t]      = __floats2half2_rn(h0x, h0y);
    o2[t + 16] = __floats2half2_rn(h1x, h1y);
    o2[t + 32] = __floats2half2_rn(h2x, h2y);

    const int woff = (PHASE == 1) ? 0 : 96;
    const float2* wn2 = (const float2*)(Wn + woff);
    float2 w0v = wn2[t], w1v = wn2[t + 16], w2v = wn2[t + 32];
    float partial = h0x * w0v.x + h0y * w0v.y + h1x * w1v.x + h1y * w1v.y +
                    h2x * w2v.x + h2y * w2v.y;
#pragma unroll
    for (int m = 8; m; m >>= 1) partial += __shfl_down(partial, m, 16);
    if (t == 0) {
        if (PHASE == 1) nodeOut[d] = partial + bn[0];
        else            nodeOut[d] += partial;
    }
}

// ---------------- graph pooling + graph head (fp16 H inputs, 2x node unroll) ----------------
__global__ __launch_bounds__(768) void k_pool(const __half* __restrict__ h1,
                                              const __half* __restrict__ h2,
                                              const int* __restrict__ batch,
                                              const float* __restrict__ Wg,
                                              const float* __restrict__ bg,
                                              float* __restrict__ out) {
    int g = blockIdx.x;
    int tid = threadIdx.x;       // 0..767
    int way = tid / 192;         // 0..3
    int f = tid - way * 192;     // 0..191

    int lo = 0, hi = NN;
    while (lo < hi) { int mid = (lo + hi) >> 1; if (batch[mid] < g) lo = mid + 1; else hi = mid; }
    int start = lo;
    hi = NN;
    while (lo < hi) { int mid = (lo + hi) >> 1; if (batch[mid] < g + 1) lo = mid + 1; else hi = mid; }
    int end = lo;

    const __half* hsrc = (f < HID) ? h1 : h2;
    int ff = (f < HID) ? f : f - HID;
    float sum = 0.f, mx = 0.f;  // h >= 0 post-relu
    int n = start + way;
    for (; n + 4 < end; n += 8) {
        float v0 = __half2float(hsrc[(size_t)n * HID + ff]);
        float v1 = __half2float(hsrc[(size_t)(n + 4) * HID + ff]);
        sum += v0 + v1;
        mx = fmaxf(mx, fmaxf(v0, v1));
    }
    if (n < end) {
        float v0 = __half2float(hsrc[(size_t)n * HID + ff]);
        sum += v0;
        mx = fmaxf(mx, v0);
    }
    __shared__ float rsum[4][192];
    __shared__ float rmax[4][192];
    rsum[way][f] = sum;
    rmax[way][f] = mx;
    __syncthreads();
    if (way == 0) {
        sum = rsum[0][f] + rsum[1][f] + rsum[2][f] + rsum[3][f];
        mx = fmaxf(fmaxf(rmax[0][f], rmax[1][f]), fmaxf(rmax[2][f], rmax[3][f]));
        float cnt = (float)(end - start);
        float mean = sum / fmaxf(cnt, 1.0f);
        rsum[0][f] = mean * Wg[f] + mx * Wg[192 + f];
    }
    __syncthreads();
    if (tid < 64) {
        float acc = rsum[0][tid] + rsum[0][tid + 64] + rsum[0][tid + 128];
#pragma unroll
        for (int m = 32; m; m >>= 1) acc += __shfl_down(acc, m, 64);
        if (tid == 0) out[g] = acc + bg[0];
    }
}

extern "C" void kernel_launch(void* const* d_in, const int* in_sizes, int n_in,
                              void* d_out, int out_size, void* d_ws, size_t ws_size,
                              hipStream_t stream) {
    const float* x    = (const float*)d_in[0];
    const int*   ei   = (const int*)d_in[1];
    const int*   srcp = ei;
    const int*   dstp = ei + NE;
    const int*   batch = (const int*)d_in[2];
    const float* W1 = (const float*)d_in[3];
    const float* b1 = (const float*)d_in[4];
    const float* W2 = (const float*)d_in[5];
    const float* b2 = (const float*)d_in[6];
    const float* Wn = (const float*)d_in[7];
    const float* bn = (const float*)d_in[8];
    const float* Wg = (const float*)d_in[9];
    const float* bg = (const float*)d_in[10];
    float* out = (float*)d_out;

    char* p = (char*)d_ws;
    auto alloc = [&](size_t bytes) {
        char* r = p;
        p += (bytes + 255) & ~(size_t)255;
        return (void*)r;
    };
    float*    dis    = (float*)alloc(NN * 4);
    int*      off    = (int*)alloc((NN + 1) * 4);
    int*      boff   = (int*)alloc((NBK + 1) * 4);
    int*      histAB = (int*)alloc((size_t)A_BLOCKS * NBK * 4);
    unsigned* tmp    = (unsigned*)alloc((size_t)NE * 4);
    int*      ssrc   = (int*)alloc((size_t)NE * 4);
    __half*   Ah     = (__half*)alloc((size_t)NN * HID * 2);   // hw buffer (both convs)
    __half*   H1h    = (__half*)alloc((size_t)NN * HID * 2);
    __half*   H2h    = (__half*)alloc((size_t)NN * HID * 2);
    __half*   W1frag = (__half*)alloc(12288 * 2);
    __half*   W2frag = (__half*)alloc(9216 * 2);

    const int TPB = 256;

    // CSR build + weight pack: [A1 ∥ pack] ; scanS ; [A3 ∥ gemm1-MFMA] ; fused B
    k_pack_a1<<<A_BLOCKS + 11, TPB, 0, stream>>>(dstp, histAB, W1, W2, W1frag, W2frag);
    k_scanS<<<1, 256, 0, stream>>>(histAB, boff);
    k_gemm1_a3<<<A_BLOCKS + GEMM1_BLOCKS, 256, 0, stream>>>(
        x, W1frag, Ah, srcp, dstp, boff, histAB, tmp);
    k_B<<<NBK, 256, 0, stream>>>(tmp, boff, off, dis, ssrc);

    const int aggThreads = NN * 16;
    float* nodeOut = out + NG;

    // conv1 aggregate (16-lane half2): H1h ; nodeOut partial 1
    k_agg<1><<<(aggThreads + TPB - 1) / TPB, TPB, 0, stream>>>(Ah, ssrc, off, dis, b1, Wn, bn, H1h, nodeOut);

    // conv2 transform (MFMA, standalone)
    k_gemm2<<<G2_BLOCKS, 256, 0, stream>>>(H1h, W2frag, Ah);

    // conv2 aggregate: H2h ; nodeOut partial 2
    k_agg<2><<<(aggThreads + TPB - 1) / TPB, TPB, 0, stream>>>(Ah, ssrc, off, dis, b2, Wn, bn, H2h, nodeOut);

    // pooling + graph head
    k_pool<<<NG, 768, 0, stream>>>(H1h, H2h, batch, Wg, bg, out);
}

// Round 19
// 238.589 us; speedup vs baseline: 1.3975x; 1.0133x over previous
//
#include <hip/hip_runtime.h>
#include <hip/hip_fp16.h>

#define NN 100000      // nodes
#define NE 1600000     // edges
#define INC 128        // in channels
#define HID 96         // hidden
#define NG 512         // graphs

#define GEMM1_BLOCKS 1563        // ceil(NN/64)
#define G2_BLOCKS 1563           // ceil(NN/64) for MFMA gemm2

#define BK_SHIFT 8
#define BK_SIZE 256
#define NBK 391                  // ceil(NN/256)
#define A_EPB 4096               // edges per A-pass block
#define A_BLOCKS 391             // ceil(NE/4096)

typedef _Float16 half8 __attribute__((ext_vector_type(8)));
typedef float f32x4 __attribute__((ext_vector_type(4)));

// ---------------- FUSED: A1 (per-block bucket histogram) ∥ W1+W2 frag pack ----------------
__global__ __launch_bounds__(256) void k_pack_a1(const int* __restrict__ dst,
                                                 int* __restrict__ histAB,
                                                 const float* __restrict__ W1,
                                                 const float* __restrict__ W2,
                                                 __half* __restrict__ W1frag,
                                                 __half* __restrict__ W2frag) {
    const int tid = threadIdx.x;
    if (blockIdx.x < A_BLOCKS) {
        __shared__ int cnt[NBK];
        int ab = blockIdx.x;
        for (int i = tid; i < NBK; i += 256) cnt[i] = 0;
        __syncthreads();
        int e0 = ab * A_EPB;
#pragma unroll 4
        for (int q = 0; q < A_EPB / 256; ++q) {
            int e = e0 + q * 256 + tid;
            if (e < NE) atomicAdd(&cnt[dst[e] >> BK_SHIFT], 1);
        }
        __syncthreads();
        for (int i = tid; i < NBK; i += 256) histAB[ab * NBK + i] = cnt[i];
        return;
    }
    int p = (blockIdx.x - A_BLOCKS) * 256 + tid;
    if (p < 1536) {
        int kc = p / 384;
        int rem = p - kc * 384;
        int ct = rem >> 6;
        int l = rem & 63;
#pragma unroll
        for (int i = 0; i < 8; ++i) {
            int k = kc * 32 + ((l >> 4) << 3) + i;
            int c = ct * 16 + (l & 15);
            W1frag[p * 8 + i] = __float2half(W1[k * HID + c]);
        }
    } else {
        int q = p - 1536;
        if (q >= 1152) return;
        int kc = q / 384;
        int rem = q - kc * 384;
        int ct = rem >> 6;
        int l = rem & 63;
#pragma unroll
        for (int i = 0; i < 8; ++i) {
            int k = kc * 32 + ((l >> 4) << 3) + i;
            int c = ct * 16 + (l & 15);
            W2frag[q * 8 + i] = __float2half(W2[k * HID + c]);
        }
    }
}

// ---------------- scanS: column prefix of histAB + bucket prefix -> boff ----------------
__global__ __launch_bounds__(512) void k_scanS(int* __restrict__ histAB, int* __restrict__ boff) {
    __shared__ int tot[512];
    int t = threadIdx.x;
    int run = 0;
    if (t < NBK) {
        for (int blk = 0; blk < A_BLOCKS; ++blk) {
            int idx = blk * NBK + t;
            int v = histAB[idx];
            histAB[idx] = run;
            run += v;
        }
    }
    tot[t] = (t < NBK) ? run : 0;
    __syncthreads();
    for (int ofs = 1; ofs < 512; ofs <<= 1) {
        int v = (t >= ofs) ? tot[t - ofs] : 0;
        __syncthreads();
        tot[t] += v;
        __syncthreads();
    }
    if (t == 0) boff[0] = 0;
    if (t < NBK) boff[t + 1] = tot[t];
}

// ---------------- FUSED: A3 (binned edge write) ∥ gemm1 (MFMA fp16) ----------------
__global__ __launch_bounds__(256) void k_gemm1_a3(
        const float* __restrict__ X, const __half* __restrict__ W1frag,
        __half* __restrict__ Yh,
        const int* __restrict__ src, const int* __restrict__ dst,
        const int* __restrict__ boff, const int* __restrict__ histAB,
        unsigned* __restrict__ tmp) {
    __shared__ __half w1s[12288];
    const int tid = threadIdx.x;

    if (blockIdx.x < A_BLOCKS) {
        int* base = (int*)w1s;
        int* lcnt = base + NBK;
        int ab = blockIdx.x;
        for (int i = tid; i < NBK; i += 256) {
            base[i] = boff[i] + histAB[ab * NBK + i];
            lcnt[i] = 0;
        }
        __syncthreads();
        int e0 = ab * A_EPB;
#pragma unroll 4
        for (int q = 0; q < A_EPB / 256; ++q) {
            int e = e0 + q * 256 + tid;
            if (e < NE) {
                int d = dst[e];
                int bk = d >> BK_SHIFT;
                int lp = atomicAdd(&lcnt[bk], 1);
                tmp[base[bk] + lp] = (unsigned)src[e] | ((unsigned)(d & (BK_SIZE - 1)) << 17);
            }
        }
        return;
    }

    // ---- gemm1 MFMA body (K = 128, 4 steps) ----
    {
        half8* d8 = (half8*)w1s;
        const half8* s8 = (const half8*)W1frag;
        for (int i = tid; i < 1536; i += 256) d8[i] = s8[i];
    }
    __syncthreads();
    const int w = tid >> 6;
    const int l = tid & 63;
    const int row0 = (blockIdx.x - A_BLOCKS) * 64 + w * 16;
    int arow = row0 + (l & 15);
    if (arow >= NN) arow = NN - 1;
    f32x4 acc[6] = {};
#pragma unroll
    for (int kc = 0; kc < 4; ++kc) {
        const float* xp = &X[(size_t)arow * INC + kc * 32 + ((l >> 4) << 3)];
        float4 xa = *(const float4*)xp;
        float4 xb = *(const float4*)(xp + 4);
        half8 a;
        a[0] = (_Float16)xa.x; a[1] = (_Float16)xa.y;
        a[2] = (_Float16)xa.z; a[3] = (_Float16)xa.w;
        a[4] = (_Float16)xb.x; a[5] = (_Float16)xb.y;
        a[6] = (_Float16)xb.z; a[7] = (_Float16)xb.w;
#pragma unroll
        for (int ct = 0; ct < 6; ++ct) {
            half8 b = *(const half8*)&w1s[((kc * 6 + ct) * 64 + l) * 8];
            acc[ct] = __builtin_amdgcn_mfma_f32_16x16x32_f16(a, b, acc[ct], 0, 0, 0);
        }
    }
    const int orow = row0 + ((l >> 4) << 2);
    const int col = l & 15;
#pragma unroll
    for (int ct = 0; ct < 6; ++ct)
#pragma unroll
        for (int i = 0; i < 4; ++i) {
            int r = orow + i;
            if (r < NN) Yh[(size_t)r * HID + ct * 16 + col] = __float2half(acc[ct][i]);
        }
}

// ---------------- B1: per-bucket degree count -> off (+dis); 1 node/thread ----------------
__global__ __launch_bounds__(256) void k_B1(const unsigned* __restrict__ tmp,
                                            const int* __restrict__ boff,
                                            int* __restrict__ off, float* __restrict__ dis) {
    __shared__ int cnt[BK_SIZE];
    __shared__ int psum[256];
    const int t = threadIdx.x;
    const int b = blockIdx.x;
    const int nb = b << BK_SHIFT;
    const int rbeg = boff[b], rend = boff[b + 1];
    cnt[t] = 0;
    __syncthreads();
    for (int e = rbeg + t; e < rend; e += 256) {
        unsigned u = tmp[e];
        atomicAdd(&cnt[u >> 17], 1);
    }
    __syncthreads();
    int c = cnt[t];
    psum[t] = c;
    __syncthreads();
    for (int ofs = 1; ofs < 256; ofs <<= 1) {
        int v = (t >= ofs) ? psum[t - ofs] : 0;
        __syncthreads();
        psum[t] += v;
        __syncthreads();
    }
    int node = nb + t;
    if (node < NN) {
        off[node] = rbeg + psum[t] - c;
        dis[node] = rsqrtf((float)(c + 1));
    }
    if (b == NBK - 1 && t == 0) off[NN] = rend;
}

// ---------------- B2: per-bucket scatter into final CSR {src, w} ----------------
__global__ __launch_bounds__(256) void k_B2(const unsigned* __restrict__ tmp,
                                            const int* __restrict__ boff,
                                            const int* __restrict__ off,
                                            const float* __restrict__ dis,
                                            int2* __restrict__ ssrcw) {
    __shared__ int cnt[BK_SIZE];
    const int t = threadIdx.x;
    const int b = blockIdx.x;
    const int nb = b << BK_SHIFT;
    const int rbeg = boff[b], rend = boff[b + 1];
    cnt[t] = 0;
    __syncthreads();
    for (int e = rbeg + t; e < rend; e += 256) {
        unsigned u = tmp[e];
        int s = (int)(u & 0x1FFFFu);
        int dl = (int)(u >> 17);
        int d = nb + dl;
        int pos = off[d] + atomicAdd(&cnt[dl], 1);
        float w = dis[s] * dis[d];
        ssrcw[pos] = make_int2(s, __float_as_int(w));
    }
}

// ---------------- GEMM2 (MFMA fp16, standalone; layout HW-validated round 10) ----------------
__global__ __launch_bounds__(256) void k_gemm2(const __half* __restrict__ Xh,
                                               const __half* __restrict__ W2frag,
                                               __half* __restrict__ Yh) {
    __shared__ __half w2s[9216];
    const int tid = threadIdx.x;
    {
        half8* d8 = (half8*)w2s;
        const half8* s8 = (const half8*)W2frag;
        for (int i = tid; i < 1152; i += 256) d8[i] = s8[i];
    }
    __syncthreads();
    const int w = tid >> 6;
    const int l = tid & 63;
    const int row0 = blockIdx.x * 64 + w * 16;
    int arow = row0 + (l & 15);
    if (arow >= NN) arow = NN - 1;
    f32x4 acc[6] = {};
#pragma unroll
    for (int kc = 0; kc < 3; ++kc) {
        half8 a = *(const half8*)&Xh[(size_t)arow * HID + kc * 32 + ((l >> 4) << 3)];
#pragma unroll
        for (int ct = 0; ct < 6; ++ct) {
            half8 b = *(const half8*)&w2s[((kc * 6 + ct) * 64 + l) * 8];
            acc[ct] = __builtin_amdgcn_mfma_f32_16x16x32_f16(a, b, acc[ct], 0, 0, 0);
        }
    }
    const int orow = row0 + ((l >> 4) << 2);
    const int col = l & 15;
#pragma unroll
    for (int ct = 0; ct < 6; ++ct)
#pragma unroll
        for (int i = 0; i < 4; ++i) {
            int r = orow + i;
            if (r < NN) Yh[(size_t)r * HID + ct * 16 + col] = __float2half(acc[ct][i]);
        }
}

// ---------------- agg batch helper: B edges, int2 descriptors ----------------
template <int B>
__device__ __forceinline__ void agg_batch(const __half* __restrict__ Ah,
                                          const int2* __restrict__ ssrcw, int j, int t,
                                          float& a0x, float& a0y, float& a1x, float& a1y,
                                          float& a2x, float& a2y) {
    int2 e[B];
#pragma unroll
    for (int q = 0; q < B; ++q) e[q] = ssrcw[j + q];
    float w[B];
    const __half2* ap[B];
#pragma unroll
    for (int q = 0; q < B; ++q) {
        w[q] = __int_as_float(e[q].y);
        ap[q] = (const __half2*)(Ah + (size_t)e[q].x * HID);
    }
    __half2 g0[B], g1[B], g2[B];
#pragma unroll
    for (int q = 0; q < B; ++q) {
        g0[q] = ap[q][t];
        g1[q] = ap[q][t + 16];
        g2[q] = ap[q][t + 32];
    }
#pragma unroll
    for (int q = 0; q < B; ++q) {
        float2 f0 = __half22float2(g0[q]);
        float2 f1 = __half22float2(g1[q]);
        float2 f2 = __half22float2(g2[q]);
        a0x += f0.x * w[q]; a0y += f0.y * w[q];
        a1x += f1.x * w[q]; a1y += f1.y * w[q];
        a2x += f2.x * w[q]; a2y += f2.y * w[q];
    }
}

// ---------------- fused GCN aggregation + node-logit partial (16 lanes/dst, half2) ------
template <int PHASE>
__global__ __launch_bounds__(256) void k_agg(const __half* __restrict__ Ah,
                                             const int2* __restrict__ ssrcw,
                                             const int* __restrict__ off,
                                             const float* __restrict__ dis,
                                             const float* __restrict__ bias,
                                             const float* __restrict__ Wn,
                                             const float* __restrict__ bn,
                                             __half* __restrict__ outh,
                                             float* __restrict__ nodeOut) {
    int gid = blockIdx.x * blockDim.x + threadIdx.x;
    int d = gid >> 4;
    int t = gid & 15;
    if (d >= NN) return;
    const int beg = off[d], end = off[d + 1];
    const float dd = dis[d];
    const __half2* ad2 = (const __half2*)(Ah + (size_t)d * HID);
    float2 s0 = __half22float2(ad2[t]);
    float2 s1 = __half22float2(ad2[t + 16]);
    float2 s2 = __half22float2(ad2[t + 32]);
    const float dd2 = dd * dd;
    float a0x = s0.x * dd2, a0y = s0.y * dd2;
    float a1x = s1.x * dd2, a1y = s1.y * dd2;
    float a2x = s2.x * dd2, a2y = s2.y * dd2;
    int j = beg;
    for (; j + 11 < end; j += 12)
        agg_batch<12>(Ah, ssrcw, j, t, a0x, a0y, a1x, a1y, a2x, a2y);
    for (; j + 3 < end; j += 4)
        agg_batch<4>(Ah, ssrcw, j, t, a0x, a0y, a1x, a1y, a2x, a2y);
    for (; j < end; ++j) {
        int2 e0 = ssrcw[j];
        float w0 = __int_as_float(e0.y);
        const __half2* a0 = (const __half2*)(Ah + (size_t)e0.x * HID);
        float2 f0 = __half22float2(a0[t]);
        float2 f1 = __half22float2(a0[t + 16]);
        float2 f2 = __half22float2(a0[t + 32]);
        a0x += f0.x * w0; a0y += f0.y * w0;
        a1x += f1.x * w0; a1y += f1.y * w0;
        a2x += f2.x * w0; a2y += f2.y * w0;
    }
    const float2* b2p = (const float2*)bias;
    float2 b0 = b2p[t], b1 = b2p[t + 16], b2 = b2p[t + 32];
    float h0x = fmaxf(a0x + b0.x, 0.f), h0y = fmaxf(a0y + b0.y, 0.f);
    float h1x = fmaxf(a1x + b1.x, 0.f), h1y = fmaxf(a1y + b1.y, 0.f);
    float h2x = fmaxf(a2x + b2.x, 0.f), h2y = fmaxf(a2y + b2.y, 0.f);
    __half2* o2 = (__half2*)(outh + (size_t)d * HID);
    o2[t]      = __floats2half2_rn(h0x, h0y);
    o2[t + 16] = __floats2half2_rn(h1x, h1y);
    o2[t + 32] = __floats2half2_rn(h2x, h2y);

    const int woff = (PHASE == 1) ? 0 : 96;
    const float2* wn2 = (const float2*)(Wn + woff);
    float2 w0v = wn2[t], w1v = wn2[t + 16], w2v = wn2[t + 32];
    float partial = h0x * w0v.x + h0y * w0v.y + h1x * w1v.x + h1y * w1v.y +
                    h2x * w2v.x + h2y * w2v.y;
#pragma unroll
    for (int m = 8; m; m >>= 1) partial += __shfl_down(partial, m, 16);
    if (t == 0) {
        if (PHASE == 1) nodeOut[d] = partial + bn[0];
        else            nodeOut[d] += partial;
    }
}

// ---------------- graph pooling + graph head (fp16 H inputs, 2x node unroll) ----------------
__global__ __launch_bounds__(768) void k_pool(const __half* __restrict__ h1,
                                              const __half* __restrict__ h2,
                                              const int* __restrict__ batch,
                                              const float* __restrict__ Wg,
                                              const float* __restrict__ bg,
                                              float* __restrict__ out) {
    int g = blockIdx.x;
    int tid = threadIdx.x;       // 0..767
    int way = tid / 192;         // 0..3
    int f = tid - way * 192;     // 0..191

    int lo = 0, hi = NN;
    while (lo < hi) { int mid = (lo + hi) >> 1; if (batch[mid] < g) lo = mid + 1; else hi = mid; }
    int start = lo;
    hi = NN;
    while (lo < hi) { int mid = (lo + hi) >> 1; if (batch[mid] < g + 1) lo = mid + 1; else hi = mid; }
    int end = lo;

    const __half* hsrc = (f < HID) ? h1 : h2;
    int ff = (f < HID) ? f : f - HID;
    float sum = 0.f, mx = 0.f;  // h >= 0 post-relu
    int n = start + way;
    for (; n + 4 < end; n += 8) {
        float v0 = __half2float(hsrc[(size_t)n * HID + ff]);
        float v1 = __half2float(hsrc[(size_t)(n + 4) * HID + ff]);
        sum += v0 + v1;
        mx = fmaxf(mx, fmaxf(v0, v1));
    }
    if (n < end) {
        float v0 = __half2float(hsrc[(size_t)n * HID + ff]);
        sum += v0;
        mx = fmaxf(mx, v0);
    }
    __shared__ float rsum[4][192];
    __shared__ float rmax[4][192];
    rsum[way][f] = sum;
    rmax[way][f] = mx;
    __syncthreads();
    if (way == 0) {
        sum = rsum[0][f] + rsum[1][f] + rsum[2][f] + rsum[3][f];
        mx = fmaxf(fmaxf(rmax[0][f], rmax[1][f]), fmaxf(rmax[2][f], rmax[3][f]));
        float cnt = (float)(end - start);
        float mean = sum / fmaxf(cnt, 1.0f);
        rsum[0][f] = mean * Wg[f] + mx * Wg[192 + f];
    }
    __syncthreads();
    if (tid < 64) {
        float acc = rsum[0][tid] + rsum[0][tid + 64] + rsum[0][tid + 128];
#pragma unroll
        for (int m = 32; m; m >>= 1) acc += __shfl_down(acc, m, 64);
        if (tid == 0) out[g] = acc + bg[0];
    }
}

extern "C" void kernel_launch(void* const* d_in, const int* in_sizes, int n_in,
                              void* d_out, int out_size, void* d_ws, size_t ws_size,
                              hipStream_t stream) {
    const float* x    = (const float*)d_in[0];
    const int*   ei   = (const int*)d_in[1];
    const int*   srcp = ei;
    const int*   dstp = ei + NE;
    const int*   batch = (const int*)d_in[2];
    const float* W1 = (const float*)d_in[3];
    const float* b1 = (const float*)d_in[4];
    const float* W2 = (const float*)d_in[5];
    const float* b2 = (const float*)d_in[6];
    const float* Wn = (const float*)d_in[7];
    const float* bn = (const float*)d_in[8];
    const float* Wg = (const float*)d_in[9];
    const float* bg = (const float*)d_in[10];
    float* out = (float*)d_out;

    char* p = (char*)d_ws;
    auto alloc = [&](size_t bytes) {
        char* r = p;
        p += (bytes + 255) & ~(size_t)255;
        return (void*)r;
    };
    float*    dis    = (float*)alloc(NN * 4);
    int*      off    = (int*)alloc((NN + 1) * 4);
    int*      boff   = (int*)alloc((NBK + 1) * 4);
    int*      histAB = (int*)alloc((size_t)A_BLOCKS * NBK * 4);
    unsigned* tmp    = (unsigned*)alloc((size_t)NE * 4);
    int2*     ssrcw  = (int2*)alloc((size_t)NE * 8);
    __half*   Ah     = (__half*)alloc((size_t)NN * HID * 2);   // hw buffer (both convs)
    __half*   H1h    = (__half*)alloc((size_t)NN * HID * 2);
    __half*   H2h    = (__half*)alloc((size_t)NN * HID * 2);
    __half*   W1frag = (__half*)alloc(12288 * 2);
    __half*   W2frag = (__half*)alloc(9216 * 2);

    const int TPB = 256;

    // CSR build + weight pack: [A1 ∥ pack] ; scanS ; [A3 ∥ gemm1-MFMA] ; B1 ; B2
    k_pack_a1<<<A_BLOCKS + 11, TPB, 0, stream>>>(dstp, histAB, W1, W2, W1frag, W2frag);
    k_scanS<<<1, 512, 0, stream>>>(histAB, boff);
    k_gemm1_a3<<<A_BLOCKS + GEMM1_BLOCKS, 256, 0, stream>>>(
        x, W1frag, Ah, srcp, dstp, boff, histAB, tmp);
    k_B1<<<NBK, 256, 0, stream>>>(tmp, boff, off, dis);
    k_B2<<<NBK, 256, 0, stream>>>(tmp, boff, off, dis, ssrcw);

    const int aggThreads = NN * 16;
    float* nodeOut = out + NG;

    // conv1 aggregate (16-lane half2): H1h ; nodeOut partial 1
    k_agg<1><<<(aggThreads + TPB - 1) / TPB, TPB, 0, stream>>>(Ah, ssrcw, off, dis, b1, Wn, bn, H1h, nodeOut);

    // conv2 transform (MFMA, standalone)
    k_gemm2<<<G2_BLOCKS, 256, 0, stream>>>(H1h, W2frag, Ah);

    // conv2 aggregate: H2h ; nodeOut partial 2
    k_agg<2><<<(aggThreads + TPB - 1) / TPB, TPB, 0, stream>>>(Ah, ssrcw, off, dis, b2, Wn, bn, H2h, nodeOut);

    // pooling + graph head
    k_pool<<<NG, 768, 0, stream>>>(H1h, H2h, batch, Wg, bg, out);
}